// Round 6
// baseline (89.567 us; speedup 1.0000x reference)
//
#include <hip/hip_runtime.h>
#include <cstddef>
#include <cstdint>

#define SS 2048
#define DD 128
#define NB 8

typedef __attribute__((ext_vector_type(8))) short short8;
typedef __attribute__((ext_vector_type(16))) float f32x16;

// ---- workspace layout (bytes) ----
#define WS_A2   0
#define WS_KV   (NB*SS*4)              // 65536
#define WS_KMX  (2*NB*SS*4)            // 131072
#define WS_KMN  (WS_KMX + 128)
#define WS_XHI  (WS_KMX + 1024)        // 132096 (16B aligned)
#define TILE_BYTES 32768               // 128 d x 128 t x 2B, swizzled
#define XARR_BYTES (NB*16*TILE_BYTES)  // 4 MiB
#define WS_XLO  (WS_XHI + XARR_BYTES)
#define WS_NEED (size_t)(WS_XLO + XARR_BYTES)

// ---------------- Kernel A+P fused: projections + X split/transpose ----------
// blocks [0,512): xsplit  — X -> bf16 hi/lo, [d][t] transposed, XOR-swizzled:
//   tile (b,T): byte(d,tt) = d*256 + ((tt*2) ^ ((d&7)<<4))
// blocks [512,576): prep  — a2[row] = (x.rsum)*(1/sqrt(128))*log2e ; k[row]=x.ent
__global__ __launch_bounds__(256) void prep_all(
    const float* __restrict__ X, const float* __restrict__ rotp,
    const float* __restrict__ entp, uint8_t* __restrict__ ws) {
  const int blk = blockIdx.x;
  const int tid = threadIdx.x;
  if (blk < 512) {
    const int b = blk >> 6;
    const int rem = blk & 63;
    const int T = rem >> 2;
    const int part = rem & 3;
    const float* xt = X + ((size_t)b * SS + T * 128) * DD;
    uint8_t* hiB = ws + WS_XHI + (size_t)(b * 16 + T) * TILE_BYTES;
    uint8_t* loB = ws + WS_XLO + (size_t)(b * 16 + T) * TILE_BYTES;
#pragma unroll
    for (int j = 0; j < 2; ++j) {
      const int chunk = part * 512 + j * 256 + tid;  // 0..2047
      const int d = chunk >> 4;                      // 0..127
      const int tg = chunk & 15;                     // 0..15
      unsigned int hi[4], lo[4];
#pragma unroll
      for (int q = 0; q < 4; ++q) {
        unsigned int h2[2], l2[2];
#pragma unroll
        for (int e = 0; e < 2; ++e) {
          const int tt = tg * 8 + q * 2 + e;
          const float v = xt[(size_t)tt * DD + d];
          const unsigned int ub = __float_as_uint(v);
          const unsigned int hb = (ub + 0x7fffu + ((ub >> 16) & 1u)) >> 16;
          const float hf = __uint_as_float(hb << 16);
          const unsigned int ul = __float_as_uint(v - hf);
          const unsigned int lb = (ul + 0x7fffu + ((ul >> 16) & 1u)) >> 16;
          h2[e] = hb; l2[e] = lb;
        }
        hi[q] = h2[0] | (h2[1] << 16);
        lo[q] = l2[0] | (l2[1] << 16);
      }
      const int off = d * 256 + ((tg * 16) ^ ((d & 7) << 4));
      *reinterpret_cast<uint4*>(hiB + off) = make_uint4(hi[0], hi[1], hi[2], hi[3]);
      *reinterpret_cast<uint4*>(loB + off) = make_uint4(lo[0], lo[1], lo[2], lo[3]);
    }
  } else {
    float* a2out = (float*)(ws + WS_A2);
    float* kout = (float*)(ws + WS_KV);
    const int p = blk - 512;            // 0..63
    const int wid = tid >> 6, lane = tid & 63;
    const int e = lane * 2;
    const float r0 = rotp[e * 3 + 0] + rotp[e * 3 + 1] + rotp[e * 3 + 2];
    const float r1 = rotp[e * 3 + 3] + rotp[e * 3 + 4] + rotp[e * 3 + 5];
    const float e0 = entp[e], e1 = entp[e + 1];
    for (int it = 0; it < 64; ++it) {
      const int row = p * 256 + wid * 64 + it;
      const float2 xv = *reinterpret_cast<const float2*>(X + (size_t)row * DD + e);
      float av = xv.x * r0 + xv.y * r1;
      float kv = xv.x * e0 + xv.y * e1;
#pragma unroll
      for (int off = 32; off > 0; off >>= 1) {
        av += __shfl_xor(av, off, 64);
        kv += __shfl_xor(kv, off, 64);
      }
      if (lane == 0) {
        a2out[row] = av * (0.08838834764831845f * 1.4426950408889634f);
        kout[row] = kv;
      }
    }
  }
}

// ---------------- Kernel B: per-batch kmax / kmin ----------------
__global__ __launch_bounds__(256) void kminmax(const float* __restrict__ kvec,
                                               float* __restrict__ kmx,
                                               float* __restrict__ kmn) {
  const int b = blockIdx.x;
  const int tid = threadIdx.x;
  float mx = -1e30f, mn = 1e30f;
  for (int i = tid; i < SS; i += 256) {
    const float v = kvec[b * SS + i];
    mx = fmaxf(mx, v);
    mn = fminf(mn, v);
  }
#pragma unroll
  for (int off = 32; off > 0; off >>= 1) {
    mx = fmaxf(mx, __shfl_xor(mx, off, 64));
    mn = fminf(mn, __shfl_xor(mn, off, 64));
  }
  __shared__ float smx[4], smn[4];
  const int wid = tid >> 6, lane = tid & 63;
  if (lane == 0) { smx[wid] = mx; smn[wid] = mn; }
  __syncthreads();
  if (tid == 0) {
    mx = fmaxf(fmaxf(smx[0], smx[1]), fmaxf(smx[2], smx[3]));
    mn = fminf(fminf(smn[0], smn[1]), fminf(smn[2], smn[3]));
    kmx[b] = mx;
    kmn[b] = mn;
  }
}

// ---------------- async global->LDS helper ----------------
typedef __attribute__((address_space(3))) unsigned int lds_u32;
typedef const __attribute__((address_space(1))) unsigned int glb_u32;
__device__ __forceinline__ void gload16(const void* g, void* l) {
  __builtin_amdgcn_global_load_lds((glb_u32*)g, (lds_u32*)l, 16, 0, 0);
}

// ---------------- Kernel C: MFMA softmax-weighted PV, 2-phase pipelined ------
// 256 blocks: b = blk&7 (XCD affinity), s-tile = blk>>3 (BM=64 rows).
// 8 waves: mh = w>>2 (32-row half), kq = w&3 (16-t quarter of the 64-t tile).
// LDS: 2 x 32KB buffers {hi 16K | lo 16K}; per-buffer tile = 64 t x 128 d,
// layout [d][128B], element t at byte (t*2)^((d&7)<<4).
__global__ __launch_bounds__(512, 2) void attn_mfma(
    const uint8_t* __restrict__ wsr, const float* __restrict__ a2,
    const float* __restrict__ kvec, const float* __restrict__ kmx,
    const float* __restrict__ kmn, float* __restrict__ out) {
  __shared__ __align__(16) uint8_t smem[65536];
  const int tid = threadIdx.x;
  const int w = tid >> 6;
  const int lane = tid & 63;
  const int lm = lane & 31;
  const int h = lane >> 5;
  const int mh = w >> 2;
  const int kq = w & 3;
  const int blk = blockIdx.x;
  const int b = blk & 7;
  const int s0 = (blk >> 3) * 64;

  const float ga = a2[b * SS + s0 + mh * 32 + lm];
  const float gm = fmaxf(ga * kmx[b], ga * kmn[b]);
  float gden = 0.0f;

  f32x16 acc[4];
#pragma unroll
  for (int nt = 0; nt < 4; ++nt)
#pragma unroll
    for (int r = 0; r < 16; ++r) acc[nt][r] = 0.0f;

  const uint8_t* hiA = wsr + WS_XHI + (size_t)b * 16 * TILE_BYTES;
  const uint8_t* loA = wsr + WS_XLO + (size_t)b * 16 * TILE_BYTES;
  const float* kb = kvec + b * SS;

  // staging geometry: wave w covers rows 16w..16w+15 (two 8-row gloads each
  // for hi and lo). lane: row += lane>>3, in-row byte = (lane&7)*16.
  const int srow = lane >> 3;
  const int scol = (lane & 7) * 16;
  const int g0 = (w * 16 + srow) * 256 + scol;       // i=0 rows global byte
  const int g1 = (w * 16 + 8 + srow) * 256 + scol;   // i=1 rows
  const int l0 = w * 2048;                            // LDS base i=0 (uniform)
  const int l1 = w * 2048 + 1024;

  // B-frag read address (within hi region of a buffer)
  const int bcol = (kq * 32 + h * 16) ^ ((lm & 7) << 4);

  int cur = 0;
  {  // prologue: stage T=0 into buf0
    const uint8_t* hT = hiA;
    const uint8_t* lT = loA;
    gload16(hT + g0, smem + l0);
    gload16(hT + g1, smem + l1);
    gload16(lT + g0, smem + 16384 + l0);
    gload16(lT + g1, smem + 16384 + l1);
  }
  __syncthreads();

  for (int T = 0; T < 32; ++T) {
    // stage next tile into the other buffer (drained by end-of-iter barrier)
    if (T < 31) {
      const int Tn = T + 1;
      const uint8_t* hT = hiA + (Tn >> 1) * TILE_BYTES + (Tn & 1) * 128;
      const uint8_t* lT = loA + (Tn >> 1) * TILE_BYTES + (Tn & 1) * 128;
      const int bb = (cur ^ 1) * 32768;
      gload16(hT + g0, smem + bb + l0);
      gload16(hT + g1, smem + bb + l1);
      gload16(lT + g0, smem + bb + 16384 + l0);
      gload16(lT + g1, smem + bb + 16384 + l1);
    }
    // A-gen: w(s=lm (+mh half), t = T*64 + kq*16 + h*8 + j), truncation split
    const int tg0 = T * 64 + kq * 16 + h * 8;
    const float4 k0 = *reinterpret_cast<const float4*>(kb + tg0);
    const float4 k1 = *reinterpret_cast<const float4*>(kb + tg0 + 4);
    const float kv8[8] = {k0.x, k0.y, k0.z, k0.w, k1.x, k1.y, k1.z, k1.w};
    short8 whi, wlo;
#pragma unroll
    for (int j = 0; j < 8; ++j) {
      const float v = exp2f(fmaf(ga, kv8[j], -gm));
      gden += v;
      const unsigned int ub = __float_as_uint(v);
      whi[j] = (short)(ub >> 16);
      const float hf = __uint_as_float(ub & 0xFFFF0000u);
      wlo[j] = (short)(__float_as_uint(v - hf) >> 16);
    }
    const uint8_t* bh_base = smem + cur * 32768;
    const uint8_t* bl_base = bh_base + 16384;
    __builtin_amdgcn_s_setprio(1);
#pragma unroll
    for (int nt = 0; nt < 4; ++nt) {
      const int a = (nt * 32 + lm) * 128 + bcol;
      const short8 bh = *reinterpret_cast<const short8*>(bh_base + a);
      const short8 bl = *reinterpret_cast<const short8*>(bl_base + a);
      acc[nt] = __builtin_amdgcn_mfma_f32_32x32x16_bf16(whi, bh, acc[nt], 0, 0, 0);
      acc[nt] = __builtin_amdgcn_mfma_f32_32x32x16_bf16(whi, bl, acc[nt], 0, 0, 0);
      acc[nt] = __builtin_amdgcn_mfma_f32_32x32x16_bf16(wlo, bh, acc[nt], 0, 0, 0);
    }
    __builtin_amdgcn_s_setprio(0);
    __syncthreads();  // drains stage loads (vmcnt) + our ds_reads; swap safe
    cur ^= 1;
  }

  // ---- cross-wave combine (reuse LDS) ----
  float* comb = reinterpret_cast<float*>(smem);           // 64x128 f32 = 32 KiB
  float* dl = reinterpret_cast<float*>(smem + 32768);     // 8 waves x 32 rows
  gden += __shfl_xor(gden, 32, 64);
  if (lane < 32) dl[w * 32 + lane] = gden;
#pragma unroll
  for (int p = 0; p < 4; ++p) {
    if (kq == p) {
#pragma unroll
      for (int nt = 0; nt < 4; ++nt)
#pragma unroll
        for (int r = 0; r < 16; ++r) {
          const int rr = (r & 3) + 8 * (r >> 2) + 4 * h;
          const int idx = (mh * 32 + rr) * 128 + nt * 32 + lm;
          if (p == 0) comb[idx] = acc[nt][r];
          else comb[idx] += acc[nt][r];
        }
    }
    __syncthreads();
  }

  // ---- epilogue: divide by denominator, store ----
  const int r = tid >> 3;            // 0..63
  const int cg = (tid & 7) * 16;
  const int rm = r & 31, rh = r >> 5;
  const float den = dl[rh * 128 + rm] + dl[rh * 128 + 32 + rm] +
                    dl[rh * 128 + 64 + rm] + dl[rh * 128 + 96 + rm];
  const float inv = 1.0f / den;
  float* orow = out + ((size_t)b * SS + s0 + r) * DD + cg;
#pragma unroll
  for (int q = 0; q < 4; ++q) {
    float4 v = *reinterpret_cast<const float4*>(comb + r * 128 + cg + q * 4);
    v.x *= inv; v.y *= inv; v.z *= inv; v.w *= inv;
    *reinterpret_cast<float4*>(orow + q * 4) = v;
  }
}

// ---------------- fallback fp32 kernel (ws too small; not expected) ---------
__global__ __launch_bounds__(256) void attn_main(
    const float* __restrict__ X, const float* __restrict__ a2,
    const float* __restrict__ kvec, const float* __restrict__ kmx,
    const float* __restrict__ kmn, float* __restrict__ out) {
  __shared__ float xs[64 * DD];
  __shared__ float wt[64 * 32];
  __shared__ float denp[8 * 32];
  const int tid = threadIdx.x;
  const int tx = tid & 15;
  const int ty = (tid >> 4) & 3;
  const int tz = tid >> 6;
  const int b = blockIdx.y;
  const int s0 = blockIdx.x * 32;
  const int sg = tid & 31;
  const int tq = tid >> 5;
  const float ga = a2[b * SS + s0 + sg];
  const float gm = fmaxf(ga * kmx[b], ga * kmn[b]);
  float gden = 0.0f;
  float acc[8][8];
#pragma unroll
  for (int r = 0; r < 8; ++r)
#pragma unroll
    for (int c = 0; c < 8; ++c) acc[r][c] = 0.0f;
  const float* xb = X + (size_t)b * SS * DD;
  const float* kb = kvec + b * SS;
  for (int t0 = 0; t0 < SS; t0 += 64) {
    __syncthreads();
#pragma unroll
    for (int rnd = 0; rnd < 8; ++rnd) {
      const int idx = rnd * 1024 + tid * 4;
      *reinterpret_cast<float4*>(xs + idx) =
          *reinterpret_cast<const float4*>(xb + t0 * DD + idx);
    }
#pragma unroll
    for (int j = 0; j < 8; ++j) {
      const float kt = kb[t0 + tq * 8 + j];
      const float wv = exp2f(fmaf(ga, kt, -gm));
      wt[(tq * 8 + j) * 32 + sg] = wv;
      gden += wv;
    }
    __syncthreads();
#pragma unroll 4
    for (int ti = 0; ti < 16; ++ti) {
      const int tl = tz * 16 + ti;
      const float4 x0 = *reinterpret_cast<const float4*>(xs + tl * DD + tx * 8);
      const float4 x1 = *reinterpret_cast<const float4*>(xs + tl * DD + tx * 8 + 4);
      const float4 w0 = *reinterpret_cast<const float4*>(wt + tl * 32 + ty * 8);
      const float4 w1 = *reinterpret_cast<const float4*>(wt + tl * 32 + ty * 8 + 4);
      const float xr[8] = {x0.x, x0.y, x0.z, x0.w, x1.x, x1.y, x1.z, x1.w};
      const float wr[8] = {w0.x, w0.y, w0.z, w0.w, w1.x, w1.y, w1.z, w1.w};
#pragma unroll
      for (int r = 0; r < 8; ++r)
#pragma unroll
        for (int c = 0; c < 8; ++c) acc[r][c] = fmaf(wr[r], xr[c], acc[r][c]);
    }
  }
  __syncthreads();
  denp[tq * 32 + sg] = gden;
  for (int p = 1; p < 4; ++p) {
    __syncthreads();
    if (tz == p) {
#pragma unroll
      for (int r = 0; r < 8; ++r) {
        const int sl = ty * 8 + r;
        *reinterpret_cast<float4*>(xs + sl * DD + tx * 8) =
            make_float4(acc[r][0], acc[r][1], acc[r][2], acc[r][3]);
        *reinterpret_cast<float4*>(xs + sl * DD + tx * 8 + 4) =
            make_float4(acc[r][4], acc[r][5], acc[r][6], acc[r][7]);
      }
    }
    __syncthreads();
    if (tz == 0) {
#pragma unroll
      for (int r = 0; r < 8; ++r) {
        const int sl = ty * 8 + r;
        const float4 v0 = *reinterpret_cast<const float4*>(xs + sl * DD + tx * 8);
        const float4 v1 = *reinterpret_cast<const float4*>(xs + sl * DD + tx * 8 + 4);
        acc[r][0] += v0.x; acc[r][1] += v0.y; acc[r][2] += v0.z; acc[r][3] += v0.w;
        acc[r][4] += v1.x; acc[r][5] += v1.y; acc[r][6] += v1.z; acc[r][7] += v1.w;
      }
    }
  }
  if (tz == 0) {
#pragma unroll
    for (int r = 0; r < 8; ++r) {
      const int sl = ty * 8 + r;
      float den = 0.0f;
#pragma unroll
      for (int q = 0; q < 8; ++q) den += denp[q * 32 + sl];
      const float inv = 1.0f / den;
      float* orow = out + ((size_t)b * SS + s0 + sl) * DD + tx * 8;
      *reinterpret_cast<float4*>(orow) =
          make_float4(acc[r][0] * inv, acc[r][1] * inv, acc[r][2] * inv, acc[r][3] * inv);
      *reinterpret_cast<float4*>(orow + 4) =
          make_float4(acc[r][4] * inv, acc[r][5] * inv, acc[r][6] * inv, acc[r][7] * inv);
    }
  }
}

extern "C" void kernel_launch(void* const* d_in, const int* in_sizes, int n_in,
                              void* d_out, int out_size, void* d_ws, size_t ws_size,
                              hipStream_t stream) {
  const float* X = (const float*)d_in[0];
  const float* rotp = (const float*)d_in[1];
  const float* entp = (const float*)d_in[2];
  float* out = (float*)d_out;
  uint8_t* ws = (uint8_t*)d_ws;

  float* a2 = (float*)(ws + WS_A2);
  float* kv = (float*)(ws + WS_KV);
  float* kmxp = (float*)(ws + WS_KMX);
  float* kmnp = (float*)(ws + WS_KMN);

  if (ws_size >= WS_NEED) {
    prep_all<<<576, 256, 0, stream>>>(X, rotp, entp, ws);
    kminmax<<<NB, 256, 0, stream>>>(kv, kmxp, kmnp);
    attn_mfma<<<256, 512, 0, stream>>>((const uint8_t*)ws, a2, kv, kmxp, kmnp, out);
  } else {
    prep_all<<<576, 256, 0, stream>>>(X, rotp, entp, ws);  // xsplit part unused
    kminmax<<<NB, 256, 0, stream>>>(kv, kmxp, kmnp);
    attn_main<<<dim3(SS / 32, NB), 256, 0, stream>>>(X, a2, kv, kmxp, kmnp, out);
  }
}

// Round 8
// 38.210 us; speedup vs baseline: 2.3441x; 2.3441x over previous
//
#include <hip/hip_runtime.h>
#include <cstddef>
#include <cstdint>

#define SS 2048
#define DD 128
#define NB 8

typedef _Float16 half8 __attribute__((ext_vector_type(8)));
typedef __attribute__((ext_vector_type(16))) float f32x16;

// ---- workspace layout (bytes) ----
#define WS_A2   0                      // NB*SS f32 (pre-folded a*log2e/sqrt(d))
#define WS_KV   (NB*SS*4)              // NB*SS f32
#define WS_XF   (2*NB*SS*4)            // 131072: fp16 tiles
#define TILE_B  32768                  // one tile: 128 d rows x 256 B (128 t fp16, swizzled)
#define WS_NEED (size_t)(WS_XF + (size_t)NB*16*TILE_B)   // ~4.33 MB
// fallback-only scratch (fits in WS_XF area)
#define WS_KMX  (WS_XF)
#define WS_KMN  (WS_XF + 128)

// ---------------- Kernel 1: fused projections + X->fp16 transpose ----------
// 512 blocks: b = blk&7 (XCD affinity matches attn), rc = blk>>3 covers rows
// [rc*32, rc*32+32). 256 thr: half-wave (32 lanes) per row, 4 d-cols/lane,
// 4 rounds of 8 rows. Tile layout: byte(d,tt) = d*256 + ((tt*2)^((d&15)<<4)).
__global__ __launch_bounds__(256) void prep(
    const float* __restrict__ X, const float* __restrict__ rotp,
    const float* __restrict__ entp, uint8_t* __restrict__ ws, int do_x) {
  const int blk = blockIdx.x;
  const int b = blk & 7;
  const int rc = blk >> 3;
  const int tid = threadIdx.x;
  const int d4 = (tid & 31) * 4;
  float* a2out = (float*)(ws + WS_A2);
  float* kout = (float*)(ws + WS_KV);

  const float4 f0 = *reinterpret_cast<const float4*>(rotp + d4 * 3);
  const float4 f1 = *reinterpret_cast<const float4*>(rotp + d4 * 3 + 4);
  const float4 f2 = *reinterpret_cast<const float4*>(rotp + d4 * 3 + 8);
  const float rs0 = f0.x + f0.y + f0.z;
  const float rs1 = f0.w + f1.x + f1.y;
  const float rs2 = f1.z + f1.w + f2.x;
  const float rs3 = f2.y + f2.z + f2.w;
  const float4 e4 = *reinterpret_cast<const float4*>(entp + d4);

#pragma unroll
  for (int rnd = 0; rnd < 4; ++rnd) {
    const int tg = rc * 32 + rnd * 8 + (tid >> 5);  // t within batch
    const float4 xv =
        *reinterpret_cast<const float4*>(X + ((size_t)b * SS + tg) * DD + d4);
    float av = xv.x * rs0 + xv.y * rs1 + xv.z * rs2 + xv.w * rs3;
    float kv = xv.x * e4.x + xv.y * e4.y + xv.z * e4.z + xv.w * e4.w;
#pragma unroll
    for (int off = 16; off > 0; off >>= 1) {
      av += __shfl_xor(av, off, 64);
      kv += __shfl_xor(kv, off, 64);
    }
    if ((tid & 31) == 0) {
      a2out[b * SS + tg] = av * (0.08838834764831845f * 1.4426950408889634f);
      kout[b * SS + tg] = kv;
    }
    if (do_x) {
      const int T = tg >> 7, tt = tg & 127;
      uint8_t* tb = ws + WS_XF + (size_t)(b * 16 + T) * TILE_B;
      const float vv[4] = {xv.x, xv.y, xv.z, xv.w};
#pragma unroll
      for (int i = 0; i < 4; ++i) {
        const int d = d4 + i;
        *reinterpret_cast<_Float16*>(tb + d * 256 + ((tt * 2) ^ ((d & 15) << 4))) =
            (_Float16)vv[i];
      }
    }
  }
}

// ---------------- async global->LDS helper ----------------
typedef __attribute__((address_space(3))) unsigned int lds_u32;
typedef const __attribute__((address_space(1))) unsigned int glb_u32;
__device__ __forceinline__ void gload16(const void* g, void* l) {
  __builtin_amdgcn_global_load_lds((glb_u32*)g, (lds_u32*)l, 16, 0, 0);
}

// ---------------- Kernel 2: MFMA softmax-weighted PV (fp16, 1-term) --------
// 512 blocks: b = blk&7, s0 = (blk>>3)*32. 8 waves = 8 disjoint 16-t k-slices
// of a 128-t tile (no LDS read amplification). dbuf 2 x 32 KB.
__global__ __launch_bounds__(512, 4) void attn_mfma(
    const uint8_t* __restrict__ ws, float* __restrict__ out) {
  __shared__ __align__(16) uint8_t smem[65536];
  __shared__ float smx[8], smn[8];
  const int tid = threadIdx.x;
  const int w = tid >> 6;
  const int lane = tid & 63;
  const int lm = lane & 31;
  const int h = lane >> 5;
  const int blk = blockIdx.x;
  const int b = blk & 7;
  const int s0 = (blk >> 3) * 32;

  const float* a2 = (const float*)(ws + WS_A2) + b * SS;
  const float* kb = (const float*)(ws + WS_KV) + b * SS;
  const uint8_t* xf = ws + WS_XF + (size_t)b * 16 * TILE_B;

  // prologue: stage tile 0 into buf0 (latency hidden under minmax reduce)
#pragma unroll
  for (int r = 0; r < 4; ++r)
    gload16(xf + r * 8192 + w * 1024 + lane * 16, smem + r * 8192 + w * 1024);

  // per-batch kmax/kmin from kv (2048 = 512 thr x 4)
  const float4 k4 = *reinterpret_cast<const float4*>(kb + tid * 4);
  float mx = fmaxf(fmaxf(k4.x, k4.y), fmaxf(k4.z, k4.w));
  float mn = fminf(fminf(k4.x, k4.y), fminf(k4.z, k4.w));
#pragma unroll
  for (int off = 32; off > 0; off >>= 1) {
    mx = fmaxf(mx, __shfl_xor(mx, off, 64));
    mn = fminf(mn, __shfl_xor(mn, off, 64));
  }
  if (lane == 0) { smx[w] = mx; smn[w] = mn; }
  const float ga = a2[s0 + lm];
  __syncthreads();  // drains stage-0 vmcnt too
  mx = smx[0]; mn = smn[0];
#pragma unroll
  for (int q = 1; q < 8; ++q) { mx = fmaxf(mx, smx[q]); mn = fminf(mn, smn[q]); }
  const float gm = fmaxf(ga * mx, ga * mn);
  float gden = 0.0f;

  f32x16 acc[4];
#pragma unroll
  for (int nt = 0; nt < 4; ++nt)
#pragma unroll
    for (int r = 0; r < 16; ++r) acc[nt][r] = 0.0f;

  const int bcol = w * 32 + h * 16;  // byte col of my 16B k-slice (pre-swizzle)
  int cur = 0;
  for (int T = 0; T < 16; ++T) {
    if (T < 15) {  // stage next tile into other buffer
      const uint8_t* tb = xf + (size_t)(T + 1) * TILE_B;
      const int bb = (cur ^ 1) << 15;
#pragma unroll
      for (int r = 0; r < 4; ++r)
        gload16(tb + r * 8192 + w * 1024 + lane * 16,
                smem + bb + r * 8192 + w * 1024);
    }
    // A-gen: w(s=lm, t = T*128 + w*16 + h*8 + j)
    const float* kp = kb + T * 128 + w * 16 + h * 8;
    const float4 ka = *reinterpret_cast<const float4*>(kp);
    const float4 kc = *reinterpret_cast<const float4*>(kp + 4);
    const float kv8[8] = {ka.x, ka.y, ka.z, ka.w, kc.x, kc.y, kc.z, kc.w};
    half8 wa;
#pragma unroll
    for (int j = 0; j < 8; ++j) {
      const float v = exp2f(fmaf(ga, kv8[j], -gm));
      gden += v;
      wa[j] = (_Float16)v;
    }
    const uint8_t* bbuf = smem + (cur << 15);
    __builtin_amdgcn_s_setprio(1);
#pragma unroll
    for (int nt = 0; nt < 4; ++nt) {
      const int d = nt * 32 + lm;
      const half8 bf = *reinterpret_cast<const half8*>(
          bbuf + d * 256 + (bcol ^ ((lm & 15) << 4)));
      acc[nt] = __builtin_amdgcn_mfma_f32_32x32x16_f16(wa, bf, acc[nt], 0, 0, 0);
    }
    __builtin_amdgcn_s_setprio(0);
    __syncthreads();  // per-wave vmcnt+lgkm drain, then swap
    cur ^= 1;
  }

  // ---- combine 8 k-slice partials (reuse LDS) ----
  float* comb = reinterpret_cast<float*>(smem);         // 32 x 128 f32 = 16 KB
  float* dl = reinterpret_cast<float*>(smem + 32768);   // 8 x 32 f32
  gden += __shfl_xor(gden, 32, 64);
  if (lane < 32) dl[w * 32 + lane] = gden;
#pragma unroll
  for (int p = 0; p < 8; ++p) {
    if (w == p) {
#pragma unroll
      for (int nt = 0; nt < 4; ++nt)
#pragma unroll
        for (int r = 0; r < 16; ++r) {
          const int rr = (r & 3) + 8 * (r >> 2) + 4 * h;
          const int idx = rr * 128 + nt * 32 + lm;
          if (p == 0) comb[idx] = acc[nt][r];
          else comb[idx] += acc[nt][r];
        }
    }
    __syncthreads();
  }

  // ---- epilogue ----
  const int r = tid >> 4;          // 0..31
  const int cg = (tid & 15) * 8;   // 0..120
  float den = 0.0f;
#pragma unroll
  for (int q = 0; q < 8; ++q) den += dl[q * 32 + r];
  const float inv = 1.0f / den;
  float* orow = out + ((size_t)b * SS + s0 + r) * DD + cg;
  float4 v0 = *reinterpret_cast<const float4*>(comb + r * 128 + cg);
  float4 v1 = *reinterpret_cast<const float4*>(comb + r * 128 + cg + 4);
  v0.x *= inv; v0.y *= inv; v0.z *= inv; v0.w *= inv;
  v1.x *= inv; v1.y *= inv; v1.z *= inv; v1.w *= inv;
  *reinterpret_cast<float4*>(orow) = v0;
  *reinterpret_cast<float4*>(orow + 4) = v1;
}

// ---------------- fallback (ws too small): fp32 path ----------------
__global__ __launch_bounds__(256) void kminmax(const float* __restrict__ kvec,
                                               float* __restrict__ kmx,
                                               float* __restrict__ kmn) {
  const int b = blockIdx.x;
  const int tid = threadIdx.x;
  float mx = -1e30f, mn = 1e30f;
  for (int i = tid; i < SS; i += 256) {
    const float v = kvec[b * SS + i];
    mx = fmaxf(mx, v);
    mn = fminf(mn, v);
  }
#pragma unroll
  for (int off = 32; off > 0; off >>= 1) {
    mx = fmaxf(mx, __shfl_xor(mx, off, 64));
    mn = fminf(mn, __shfl_xor(mn, off, 64));
  }
  __shared__ float smx[4], smn[4];
  const int wid = tid >> 6, lane = tid & 63;
  if (lane == 0) { smx[wid] = mx; smn[wid] = mn; }
  __syncthreads();
  if (tid == 0) {
    kmx[b] = fmaxf(fmaxf(smx[0], smx[1]), fmaxf(smx[2], smx[3]));
    kmn[b] = fminf(fminf(smn[0], smn[1]), fminf(smn[2], smn[3]));
  }
}

__global__ __launch_bounds__(256) void attn_main(
    const float* __restrict__ X, const float* __restrict__ a2,
    const float* __restrict__ kvec, const float* __restrict__ kmx,
    const float* __restrict__ kmn, float* __restrict__ out) {
  __shared__ float xs[64 * DD];
  __shared__ float wt[64 * 32];
  __shared__ float denp[8 * 32];
  const int tid = threadIdx.x;
  const int tx = tid & 15;
  const int ty = (tid >> 4) & 3;
  const int tz = tid >> 6;
  const int b = blockIdx.y;
  const int s0 = blockIdx.x * 32;
  const int sg = tid & 31;
  const int tq = tid >> 5;
  const float ga = a2[b * SS + s0 + sg];
  const float gm = fmaxf(ga * kmx[b], ga * kmn[b]);
  float gden = 0.0f;
  float acc[8][8];
#pragma unroll
  for (int r = 0; r < 8; ++r)
#pragma unroll
    for (int c = 0; c < 8; ++c) acc[r][c] = 0.0f;
  const float* xb = X + (size_t)b * SS * DD;
  const float* kb = kvec + b * SS;
  for (int t0 = 0; t0 < SS; t0 += 64) {
    __syncthreads();
#pragma unroll
    for (int rnd = 0; rnd < 8; ++rnd) {
      const int idx = rnd * 1024 + tid * 4;
      *reinterpret_cast<float4*>(xs + idx) =
          *reinterpret_cast<const float4*>(xb + t0 * DD + idx);
    }
#pragma unroll
    for (int j = 0; j < 8; ++j) {
      const float kt = kb[t0 + tq * 8 + j];
      const float wv = exp2f(fmaf(ga, kt, -gm));
      wt[(tq * 8 + j) * 32 + sg] = wv;
      gden += wv;
    }
    __syncthreads();
#pragma unroll 4
    for (int ti = 0; ti < 16; ++ti) {
      const int tl = tz * 16 + ti;
      const float4 x0 = *reinterpret_cast<const float4*>(xs + tl * DD + tx * 8);
      const float4 x1 = *reinterpret_cast<const float4*>(xs + tl * DD + tx * 8 + 4);
      const float4 w0 = *reinterpret_cast<const float4*>(wt + tl * 32 + ty * 8);
      const float4 w1 = *reinterpret_cast<const float4*>(wt + tl * 32 + ty * 8 + 4);
      const float xr[8] = {x0.x, x0.y, x0.z, x0.w, x1.x, x1.y, x1.z, x1.w};
      const float wr[8] = {w0.x, w0.y, w0.z, w0.w, w1.x, w1.y, w1.z, w1.w};
#pragma unroll
      for (int r = 0; r < 8; ++r)
#pragma unroll
        for (int c = 0; c < 8; ++c) acc[r][c] = fmaf(wr[r], xr[c], acc[r][c]);
    }
  }
  __syncthreads();
  denp[tq * 32 + sg] = gden;
  for (int p = 1; p < 4; ++p) {
    __syncthreads();
    if (tz == p) {
#pragma unroll
      for (int r = 0; r < 8; ++r) {
        const int sl = ty * 8 + r;
        *reinterpret_cast<float4*>(xs + sl * DD + tx * 8) =
            make_float4(acc[r][0], acc[r][1], acc[r][2], acc[r][3]);
        *reinterpret_cast<float4*>(xs + sl * DD + tx * 8 + 4) =
            make_float4(acc[r][4], acc[r][5], acc[r][6], acc[r][7]);
      }
    }
    __syncthreads();
    if (tz == 0) {
#pragma unroll
      for (int r = 0; r < 8; ++r) {
        const int sl = ty * 8 + r;
        const float4 v0 = *reinterpret_cast<const float4*>(xs + sl * DD + tx * 8);
        const float4 v1 = *reinterpret_cast<const float4*>(xs + sl * DD + tx * 8 + 4);
        acc[r][0] += v0.x; acc[r][1] += v0.y; acc[r][2] += v0.z; acc[r][3] += v0.w;
        acc[r][4] += v1.x; acc[r][5] += v1.y; acc[r][6] += v1.z; acc[r][7] += v1.w;
      }
    }
  }
  if (tz == 0) {
#pragma unroll
    for (int r = 0; r < 8; ++r) {
      const int sl = ty * 8 + r;
      float den = 0.0f;
#pragma unroll
      for (int q = 0; q < 8; ++q) den += denp[q * 32 + sl];
      const float inv = 1.0f / den;
      float* orow = out + ((size_t)b * SS + s0 + sl) * DD + tx * 8;
      *reinterpret_cast<float4*>(orow) =
          make_float4(acc[r][0] * inv, acc[r][1] * inv, acc[r][2] * inv, acc[r][3] * inv);
      *reinterpret_cast<float4*>(orow + 4) =
          make_float4(acc[r][4] * inv, acc[r][5] * inv, acc[r][6] * inv, acc[r][7] * inv);
    }
  }
}

extern "C" void kernel_launch(void* const* d_in, const int* in_sizes, int n_in,
                              void* d_out, int out_size, void* d_ws, size_t ws_size,
                              hipStream_t stream) {
  const float* X = (const float*)d_in[0];
  const float* rotp = (const float*)d_in[1];
  const float* entp = (const float*)d_in[2];
  float* out = (float*)d_out;
  uint8_t* ws = (uint8_t*)d_ws;

  if (ws_size >= WS_NEED) {
    prep<<<512, 256, 0, stream>>>(X, rotp, entp, ws, 1);
    attn_mfma<<<512, 512, 0, stream>>>((const uint8_t*)ws, out);
  } else {
    float* a2 = (float*)(ws + WS_A2);
    float* kv = (float*)(ws + WS_KV);
    float* kmxp = (float*)(ws + WS_KMX);
    float* kmnp = (float*)(ws + WS_KMN);
    prep<<<512, 256, 0, stream>>>(X, rotp, entp, ws, 0);
    kminmax<<<NB, 256, 0, stream>>>(kv, kmxp, kmnp);
    attn_main<<<dim3(SS / 32, NB), 256, 0, stream>>>(X, a2, kv, kmxp, kmnp, out);
  }
}

// Round 10
// 33.381 us; speedup vs baseline: 2.6832x; 1.1446x over previous
//
#include <hip/hip_runtime.h>
#include <cstddef>
#include <cstdint>

#define SS 2048
#define DD 128
#define NB 8

typedef _Float16 half8 __attribute__((ext_vector_type(8)));
typedef __attribute__((ext_vector_type(16))) float f32x16;

// ---- workspace layout (bytes) ----
#define WS_A2   0                      // NB*SS f32 (pre-folded a*log2e/sqrt(d))
#define WS_KV   (NB*SS*4)              // NB*SS f32
#define WS_XF   (2*NB*SS*4)            // 131072: fp16 fragment-major X^T
#define BATCH_B (SS*DD*2)              // 512 KiB per batch
#define WS_NEED (size_t)(WS_XF + (size_t)NB*BATCH_B)   // ~4.33 MB
// fallback-only scratch (fits in WS_XF area)
#define WS_KMX  (WS_XF)
#define WS_KMN  (WS_XF + 128)

// Fragment-major layout for X^T fp16, per batch:
//   element X[t][d]:  T=t>>7, t'=t&127, w=t'>>4, hh=(t'>>3)&1, j=t'&7,
//                     nt=d>>5, lm=d&31, lane=lm+(hh<<5)
//   byte = (T*8+w)*4096 + nt*1024 + lane*16 + j*2
// => wave w's B-frag (T,nt) is ONE contiguous 1 KiB block (dwordx4/lane).

// ---------------- Kernel 1: fused projections + X->fp16 fragment store -----
__global__ __launch_bounds__(256) void prep(
    const float* __restrict__ X, const float* __restrict__ rotp,
    const float* __restrict__ entp, uint8_t* __restrict__ ws, int do_x) {
  const int blk = blockIdx.x;
  const int b = blk & 7;
  const int rc = blk >> 3;
  const int tid = threadIdx.x;
  const int d4 = (tid & 31) * 4;
  float* a2out = (float*)(ws + WS_A2);
  float* kout = (float*)(ws + WS_KV);

  const float4 f0 = *reinterpret_cast<const float4*>(rotp + d4 * 3);
  const float4 f1 = *reinterpret_cast<const float4*>(rotp + d4 * 3 + 4);
  const float4 f2 = *reinterpret_cast<const float4*>(rotp + d4 * 3 + 8);
  const float rs0 = f0.x + f0.y + f0.z;
  const float rs1 = f0.w + f1.x + f1.y;
  const float rs2 = f1.z + f1.w + f2.x;
  const float rs3 = f2.y + f2.z + f2.w;
  const float4 e4 = *reinterpret_cast<const float4*>(entp + d4);

#pragma unroll
  for (int rnd = 0; rnd < 4; ++rnd) {
    const int tg = rc * 32 + rnd * 8 + (tid >> 5);  // t within batch
    const float4 xv =
        *reinterpret_cast<const float4*>(X + ((size_t)b * SS + tg) * DD + d4);
    float av = xv.x * rs0 + xv.y * rs1 + xv.z * rs2 + xv.w * rs3;
    float kv = xv.x * e4.x + xv.y * e4.y + xv.z * e4.z + xv.w * e4.w;
#pragma unroll
    for (int off = 16; off > 0; off >>= 1) {
      av += __shfl_xor(av, off, 64);
      kv += __shfl_xor(kv, off, 64);
    }
    if ((tid & 31) == 0) {
      a2out[b * SS + tg] = av * (0.08838834764831845f * 1.4426950408889634f);
      kout[b * SS + tg] = kv;
    }
    if (do_x) {
      const int T = tg >> 7;
      const int tp = tg & 127;
      const int wf = tp >> 4;
      const int hh = (tp >> 3) & 1;
      const int j = tp & 7;
      const int nt = d4 >> 5;
      const int lane0 = (d4 & 31) + (hh << 5);
      uint8_t* tb = ws + WS_XF + (size_t)b * BATCH_B +
                    (T * 8 + wf) * 4096 + nt * 1024 + j * 2;
      const float vv[4] = {xv.x, xv.y, xv.z, xv.w};
#pragma unroll
      for (int i = 0; i < 4; ++i)
        *reinterpret_cast<_Float16*>(tb + (lane0 + i) * 16) = (_Float16)vv[i];
    }
  }
}

// ---------------- Kernel 2: MFMA softmax-weighted PV, LDS-free main loop ---
// 256 blocks: b = blk&7 (XCD affinity), s0 = (blk>>3)*64. 8 waves = 8
// disjoint 16-t k-slices per 128-t tile; B-frags loaded global->VGPR
// (coalesced 1KB/wave), 1-deep prefetch, NO barriers in the main loop.
__global__ __launch_bounds__(512, 2) void attn_mfma(
    const uint8_t* __restrict__ ws, float* __restrict__ out) {
  __shared__ float comb[2][64 * 128];  // 64 KiB
  __shared__ float dl[8 * 64];
  __shared__ float smx[8], smn[8];
  const int tid = threadIdx.x;
  const int w = tid >> 6;
  const int lane = tid & 63;
  const int lm = lane & 31;
  const int h = lane >> 5;
  const int blk = blockIdx.x;
  const int b = blk & 7;
  const int s0 = (blk >> 3) * 64;

  const float* a2 = (const float*)(ws + WS_A2) + b * SS;
  const float* kb = (const float*)(ws + WS_KV) + b * SS;
  const uint8_t* xf = ws + WS_XF + (size_t)b * BATCH_B;

  // per-batch kmax/kmin (512 thr x 4)
  const float4 k4 = *reinterpret_cast<const float4*>(kb + tid * 4);
  float mx = fmaxf(fmaxf(k4.x, k4.y), fmaxf(k4.z, k4.w));
  float mn = fminf(fminf(k4.x, k4.y), fminf(k4.z, k4.w));
#pragma unroll
  for (int off = 32; off > 0; off >>= 1) {
    mx = fmaxf(mx, __shfl_xor(mx, off, 64));
    mn = fminf(mn, __shfl_xor(mn, off, 64));
  }
  if (lane == 0) { smx[w] = mx; smn[w] = mn; }
  const float ga0 = a2[s0 + lm];
  const float ga1 = a2[s0 + 32 + lm];
  __syncthreads();
  mx = smx[0]; mn = smn[0];
#pragma unroll
  for (int q = 1; q < 8; ++q) { mx = fmaxf(mx, smx[q]); mn = fminf(mn, smn[q]); }
  const float gm0 = fmaxf(ga0 * mx, ga0 * mn);
  const float gm1 = fmaxf(ga1 * mx, ga1 * mn);
  float gden0 = 0.0f, gden1 = 0.0f;

  f32x16 acc0[4], acc1[4];
#pragma unroll
  for (int nt = 0; nt < 4; ++nt)
#pragma unroll
    for (int r = 0; r < 16; ++r) { acc0[nt][r] = 0.0f; acc1[nt][r] = 0.0f; }

  const uint8_t* wb = xf + w * 4096 + lane * 16;  // my frag base
  half8 bf[4];
#pragma unroll
  for (int nt = 0; nt < 4; ++nt)
    bf[nt] = *reinterpret_cast<const half8*>(wb + nt * 1024);

  for (int T = 0; T < 16; ++T) {
    half8 bn[4];
    if (T < 15) {
      const uint8_t* nb_ = wb + (T + 1) * 32768;
#pragma unroll
      for (int nt = 0; nt < 4; ++nt)
        bn[nt] = *reinterpret_cast<const half8*>(nb_ + nt * 1024);
    }
    // A-gen: w(s, t = T*128 + w*16 + h*8 + j)
    const float* kp = kb + T * 128 + w * 16 + h * 8;
    const float4 ka = *reinterpret_cast<const float4*>(kp);
    const float4 kc = *reinterpret_cast<const float4*>(kp + 4);
    const float kv8[8] = {ka.x, ka.y, ka.z, ka.w, kc.x, kc.y, kc.z, kc.w};
    half8 wa0, wa1;
#pragma unroll
    for (int j = 0; j < 8; ++j) {
      const float v0 = exp2f(fmaf(ga0, kv8[j], -gm0));
      const float v1 = exp2f(fmaf(ga1, kv8[j], -gm1));
      gden0 += v0; gden1 += v1;
      wa0[j] = (_Float16)v0;
      wa1[j] = (_Float16)v1;
    }
    __builtin_amdgcn_s_setprio(1);
#pragma unroll
    for (int nt = 0; nt < 4; ++nt) {
      acc0[nt] = __builtin_amdgcn_mfma_f32_32x32x16_f16(wa0, bf[nt], acc0[nt], 0, 0, 0);
      acc1[nt] = __builtin_amdgcn_mfma_f32_32x32x16_f16(wa1, bf[nt], acc1[nt], 0, 0, 0);
    }
    __builtin_amdgcn_s_setprio(0);
#pragma unroll
    for (int nt = 0; nt < 4; ++nt) bf[nt] = bn[nt];
  }

  // ---- combine: two halves in parallel (waves 0-3 -> comb[0], 4-7 -> comb[1])
  gden0 += __shfl_xor(gden0, 32, 64);
  gden1 += __shfl_xor(gden1, 32, 64);
  if (lane < 32) { dl[w * 64 + lane] = gden0; dl[w * 64 + 32 + lane] = gden1; }
#pragma unroll
  for (int p = 0; p < 4; ++p) {
    const int grp = w >> 2;       // 0 or 1
    if ((w & 3) == p) {
      float* cb = comb[grp];
#pragma unroll
      for (int nt = 0; nt < 4; ++nt)
#pragma unroll
        for (int r = 0; r < 16; ++r) {
          const int rr = (r & 3) + 8 * (r >> 2) + 4 * h;
          const int i0 = rr * 128 + nt * 32 + lm;
          const int i1 = (32 + rr) * 128 + nt * 32 + lm;
          if (p == 0) { cb[i0] = acc0[nt][r]; cb[i1] = acc1[nt][r]; }
          else        { cb[i0] += acc0[nt][r]; cb[i1] += acc1[nt][r]; }
        }
    }
    __syncthreads();
  }

  // ---- epilogue: sum halves, divide by denominator, store ----
  const int r = tid >> 3;          // 0..63
  const int cg = (tid & 7) * 16;   // 0..112
  float den = 0.0f;
#pragma unroll
  for (int q = 0; q < 8; ++q) den += dl[q * 64 + r];
  const float inv = 1.0f / den;
  float* orow = out + ((size_t)b * SS + s0 + r) * DD + cg;
#pragma unroll
  for (int q = 0; q < 4; ++q) {
    const float4 vA = *reinterpret_cast<const float4*>(&comb[0][r * 128 + cg + q * 4]);
    const float4 vB = *reinterpret_cast<const float4*>(&comb[1][r * 128 + cg + q * 4]);
    *reinterpret_cast<float4*>(orow + q * 4) =
        make_float4((vA.x + vB.x) * inv, (vA.y + vB.y) * inv,
                    (vA.z + vB.z) * inv, (vA.w + vB.w) * inv);
  }
}

// ---------------- fallback (ws too small): fp32 path ----------------
__global__ __launch_bounds__(256) void kminmax(const float* __restrict__ kvec,
                                               float* __restrict__ kmx,
                                               float* __restrict__ kmn) {
  const int b = blockIdx.x;
  const int tid = threadIdx.x;
  float mx = -1e30f, mn = 1e30f;
  for (int i = tid; i < SS; i += 256) {
    const float v = kvec[b * SS + i];
    mx = fmaxf(mx, v);
    mn = fminf(mn, v);
  }
#pragma unroll
  for (int off = 32; off > 0; off >>= 1) {
    mx = fmaxf(mx, __shfl_xor(mx, off, 64));
    mn = fminf(mn, __shfl_xor(mn, off, 64));
  }
  __shared__ float smx[4], smn[4];
  const int wid = tid >> 6, lane = tid & 63;
  if (lane == 0) { smx[wid] = mx; smn[wid] = mn; }
  __syncthreads();
  if (tid == 0) {
    kmx[b] = fmaxf(fmaxf(smx[0], smx[1]), fmaxf(smx[2], smx[3]));
    kmn[b] = fminf(fminf(smn[0], smn[1]), fminf(smn[2], smn[3]));
  }
}

__global__ __launch_bounds__(256) void attn_main(
    const float* __restrict__ X, const float* __restrict__ a2,
    const float* __restrict__ kvec, const float* __restrict__ kmx,
    const float* __restrict__ kmn, float* __restrict__ out) {
  __shared__ float xs[64 * DD];
  __shared__ float wt[64 * 32];
  __shared__ float denp[8 * 32];
  const int tid = threadIdx.x;
  const int tx = tid & 15;
  const int ty = (tid >> 4) & 3;
  const int tz = tid >> 6;
  const int b = blockIdx.y;
  const int s0 = blockIdx.x * 32;
  const int sg = tid & 31;
  const int tq = tid >> 5;
  const float ga = a2[b * SS + s0 + sg];
  const float gm = fmaxf(ga * kmx[b], ga * kmn[b]);
  float gden = 0.0f;
  float acc[8][8];
#pragma unroll
  for (int r = 0; r < 8; ++r)
#pragma unroll
    for (int c = 0; c < 8; ++c) acc[r][c] = 0.0f;
  const float* xb = X + (size_t)b * SS * DD;
  const float* kb = kvec + b * SS;
  for (int t0 = 0; t0 < SS; t0 += 64) {
    __syncthreads();
#pragma unroll
    for (int rnd = 0; rnd < 8; ++rnd) {
      const int idx = rnd * 1024 + tid * 4;
      *reinterpret_cast<float4*>(xs + idx) =
          *reinterpret_cast<const float4*>(xb + t0 * DD + idx);
    }
#pragma unroll
    for (int j = 0; j < 8; ++j) {
      const float kt = kb[t0 + tq * 8 + j];
      const float wv = exp2f(fmaf(ga, kt, -gm));
      wt[(tq * 8 + j) * 32 + sg] = wv;
      gden += wv;
    }
    __syncthreads();
#pragma unroll 4
    for (int ti = 0; ti < 16; ++ti) {
      const int tl = tz * 16 + ti;
      const float4 x0 = *reinterpret_cast<const float4*>(xs + tl * DD + tx * 8);
      const float4 x1 = *reinterpret_cast<const float4*>(xs + tl * DD + tx * 8 + 4);
      const float4 w0 = *reinterpret_cast<const float4*>(wt + tl * 32 + ty * 8);
      const float4 w1 = *reinterpret_cast<const float4*>(wt + tl * 32 + ty * 8 + 4);
      const float xr[8] = {x0.x, x0.y, x0.z, x0.w, x1.x, x1.y, x1.z, x1.w};
      const float wr[8] = {w0.x, w0.y, w0.z, w0.w, w1.x, w1.y, w1.z, w1.w};
#pragma unroll
      for (int r = 0; r < 8; ++r)
#pragma unroll
        for (int c = 0; c < 8; ++c) acc[r][c] = fmaf(wr[r], xr[c], acc[r][c]);
    }
  }
  __syncthreads();
  denp[tq * 32 + sg] = gden;
  for (int p = 1; p < 4; ++p) {
    __syncthreads();
    if (tz == p) {
#pragma unroll
      for (int r = 0; r < 8; ++r) {
        const int sl = ty * 8 + r;
        *reinterpret_cast<float4*>(xs + sl * DD + tx * 8) =
            make_float4(acc[r][0], acc[r][1], acc[r][2], acc[r][3]);
        *reinterpret_cast<float4*>(xs + sl * DD + tx * 8 + 4) =
            make_float4(acc[r][4], acc[r][5], acc[r][6], acc[r][7]);
      }
    }
    __syncthreads();
    if (tz == 0) {
#pragma unroll
      for (int r = 0; r < 8; ++r) {
        const int sl = ty * 8 + r;
        const float4 v0 = *reinterpret_cast<const float4*>(xs + sl * DD + tx * 8);
        const float4 v1 = *reinterpret_cast<const float4*>(xs + sl * DD + tx * 8 + 4);
        acc[r][0] += v0.x; acc[r][1] += v0.y; acc[r][2] += v0.z; acc[r][3] += v0.w;
        acc[r][4] += v1.x; acc[r][5] += v1.y; acc[r][6] += v1.z; acc[r][7] += v1.w;
      }
    }
  }
  if (tz == 0) {
#pragma unroll
    for (int r = 0; r < 8; ++r) {
      const int sl = ty * 8 + r;
      float den = 0.0f;
#pragma unroll
      for (int q = 0; q < 8; ++q) den += denp[q * 32 + sl];
      const float inv = 1.0f / den;
      float* orow = out + ((size_t)b * SS + s0 + sl) * DD + tx * 8;
      *reinterpret_cast<float4*>(orow) =
          make_float4(acc[r][0] * inv, acc[r][1] * inv, acc[r][2] * inv, acc[r][3] * inv);
      *reinterpret_cast<float4*>(orow + 4) =
          make_float4(acc[r][4] * inv, acc[r][5] * inv, acc[r][6] * inv, acc[r][7] * inv);
    }
  }
}

extern "C" void kernel_launch(void* const* d_in, const int* in_sizes, int n_in,
                              void* d_out, int out_size, void* d_ws, size_t ws_size,
                              hipStream_t stream) {
  const float* X = (const float*)d_in[0];
  const float* rotp = (const float*)d_in[1];
  const float* entp = (const float*)d_in[2];
  float* out = (float*)d_out;
  uint8_t* ws = (uint8_t*)d_ws;

  if (ws_size >= WS_NEED) {
    prep<<<512, 256, 0, stream>>>(X, rotp, entp, ws, 1);
    attn_mfma<<<256, 512, 0, stream>>>((const uint8_t*)ws, out);
  } else {
    float* a2 = (float*)(ws + WS_A2);
    float* kv = (float*)(ws + WS_KV);
    float* kmxp = (float*)(ws + WS_KMX);
    float* kmnp = (float*)(ws + WS_KMN);
    prep<<<512, 256, 0, stream>>>(X, rotp, entp, ws, 0);
    kminmax<<<NB, 256, 0, stream>>>(kv, kmxp, kmnp);
    attn_main<<<dim3(SS / 32, NB), 256, 0, stream>>>(X, a2, kv, kmxp, kmnp, out);
  }
}

// Round 11
// 31.624 us; speedup vs baseline: 2.8323x; 1.0556x over previous
//
#include <hip/hip_runtime.h>
#include <cstddef>
#include <cstdint>

#define SS 2048
#define DD 128
#define NB 8

typedef _Float16 half8 __attribute__((ext_vector_type(8)));
typedef __attribute__((ext_vector_type(16))) float f32x16;

// ---- workspace layout (bytes) ----
#define WS_A2   0                      // NB*SS f32 (pre-folded a*log2e/sqrt(d))
#define WS_KV   (NB*SS*4)              // NB*SS f32
#define WS_XF   (2*NB*SS*4)            // 131072: fp16 fragment-major X^T
#define BATCH_B (SS*DD*2)              // 512 KiB per batch
#define WS_NEED (size_t)(WS_XF + (size_t)NB*BATCH_B)   // ~4.33 MB
// fallback-only scratch (fits in WS_XF area)
#define WS_KMX  (WS_XF)
#define WS_KMN  (WS_XF + 128)

// Fragment-major layout for X^T fp16, per batch:
//   element X[t][d]:  T=t>>7, t'=t&127, w=t'>>4, hh=(t'>>3)&1, j=t'&7,
//                     nt=d>>5, lm=d&31, lane=lm+(hh<<5)
//   byte = (T*8+w)*4096 + nt*1024 + lane*16 + j*2
// => wave w's B-frag (T,nt) is ONE contiguous 1 KiB block (dwordx4/lane).

// ---------------- Kernel 1: fused projections + X->fp16 fragment store -----
// Block (b, rc) covers 32 t-rows x 128 d. Phase 1: coalesced read + projection
// reduce + fp16 into LDS [d][t31] (row stride 80 B). Phase 2: ds_read_b128 +
// fully-coalesced global_store_dwordx4 (the 32 rows = exactly two 4 KiB
// fragment blocks). This replaces R10's 2-byte/16B-stride global scatter,
// which was L2 request-rate-bound (~32 sectors per wave store).
__global__ __launch_bounds__(256) void prep(
    const float* __restrict__ X, const float* __restrict__ rotp,
    const float* __restrict__ entp, uint8_t* __restrict__ ws, int do_x) {
  __shared__ __align__(16) uint8_t lbuf[128 * 80];  // 10 KiB
  const int blk = blockIdx.x;
  const int b = blk & 7;
  const int rc = blk >> 3;
  const int tid = threadIdx.x;
  const int d4 = (tid & 31) * 4;
  float* a2out = (float*)(ws + WS_A2);
  float* kout = (float*)(ws + WS_KV);

  const float4 f0 = *reinterpret_cast<const float4*>(rotp + d4 * 3);
  const float4 f1 = *reinterpret_cast<const float4*>(rotp + d4 * 3 + 4);
  const float4 f2 = *reinterpret_cast<const float4*>(rotp + d4 * 3 + 8);
  const float rs0 = f0.x + f0.y + f0.z;
  const float rs1 = f0.w + f1.x + f1.y;
  const float rs2 = f1.z + f1.w + f2.x;
  const float rs3 = f2.y + f2.z + f2.w;
  const float4 e4 = *reinterpret_cast<const float4*>(entp + d4);

#pragma unroll
  for (int rnd = 0; rnd < 4; ++rnd) {
    const int t31 = rnd * 8 + (tid >> 5);           // 0..31 within block
    const int tg = rc * 32 + t31;                   // t within batch
    const float4 xv =
        *reinterpret_cast<const float4*>(X + ((size_t)b * SS + tg) * DD + d4);
    float av = xv.x * rs0 + xv.y * rs1 + xv.z * rs2 + xv.w * rs3;
    float kv = xv.x * e4.x + xv.y * e4.y + xv.z * e4.z + xv.w * e4.w;
#pragma unroll
    for (int off = 16; off > 0; off >>= 1) {
      av += __shfl_xor(av, off, 64);
      kv += __shfl_xor(kv, off, 64);
    }
    if ((tid & 31) == 0) {
      a2out[b * SS + tg] = av * (0.08838834764831845f * 1.4426950408889634f);
      kout[b * SS + tg] = kv;
    }
    if (do_x) {
      const float vv[4] = {xv.x, xv.y, xv.z, xv.w};
#pragma unroll
      for (int i = 0; i < 4; ++i)
        *reinterpret_cast<_Float16*>(lbuf + (d4 + i) * 80 + t31 * 2) =
            (_Float16)vv[i];
    }
  }

  if (do_x) {
    __syncthreads();
    const int T = rc >> 2;
    const int wfb = (rc & 3) * 2;
    uint8_t* outb = ws + WS_XF + (size_t)b * BATCH_B + (T * 8 + wfb) * 4096;
    const int nt = tid >> 6;
    const int lane = tid & 63;
    const int hh = lane >> 5;
    const int d = nt * 32 + (lane & 31);
#pragma unroll
    for (int wfl = 0; wfl < 2; ++wfl) {
      const half8 v = *reinterpret_cast<const half8*>(
          lbuf + d * 80 + (wfl * 16 + hh * 8) * 2);
      *reinterpret_cast<half8*>(outb + wfl * 4096 + nt * 1024 + lane * 16) = v;
    }
  }
}

// ---------------- Kernel 2: MFMA softmax-weighted PV, LDS-free main loop ---
// 256 blocks: b = blk&7 (XCD affinity), s0 = (blk>>3)*64. 8 waves = 8
// disjoint 16-t k-slices per 128-t tile; B-frags loaded global->VGPR
// (coalesced 1KB/wave), 1-deep prefetch, NO barriers in the main loop.
__global__ __launch_bounds__(512, 2) void attn_mfma(
    const uint8_t* __restrict__ ws, float* __restrict__ out) {
  __shared__ float comb[2][64 * 128];  // 64 KiB
  __shared__ float dl[8 * 64];
  __shared__ float smx[8], smn[8];
  const int tid = threadIdx.x;
  const int w = tid >> 6;
  const int lane = tid & 63;
  const int lm = lane & 31;
  const int h = lane >> 5;
  const int blk = blockIdx.x;
  const int b = blk & 7;
  const int s0 = (blk >> 3) * 64;

  const float* a2 = (const float*)(ws + WS_A2) + b * SS;
  const float* kb = (const float*)(ws + WS_KV) + b * SS;
  const uint8_t* xf = ws + WS_XF + (size_t)b * BATCH_B;

  // per-batch kmax/kmin (512 thr x 4)
  const float4 k4 = *reinterpret_cast<const float4*>(kb + tid * 4);
  float mx = fmaxf(fmaxf(k4.x, k4.y), fmaxf(k4.z, k4.w));
  float mn = fminf(fminf(k4.x, k4.y), fminf(k4.z, k4.w));
#pragma unroll
  for (int off = 32; off > 0; off >>= 1) {
    mx = fmaxf(mx, __shfl_xor(mx, off, 64));
    mn = fminf(mn, __shfl_xor(mn, off, 64));
  }
  if (lane == 0) { smx[w] = mx; smn[w] = mn; }
  const float ga0 = a2[s0 + lm];
  const float ga1 = a2[s0 + 32 + lm];
  __syncthreads();
  mx = smx[0]; mn = smn[0];
#pragma unroll
  for (int q = 1; q < 8; ++q) { mx = fmaxf(mx, smx[q]); mn = fminf(mn, smn[q]); }
  const float gm0 = fmaxf(ga0 * mx, ga0 * mn);
  const float gm1 = fmaxf(ga1 * mx, ga1 * mn);
  float gden0 = 0.0f, gden1 = 0.0f;

  f32x16 acc0[4], acc1[4];
#pragma unroll
  for (int nt = 0; nt < 4; ++nt)
#pragma unroll
    for (int r = 0; r < 16; ++r) { acc0[nt][r] = 0.0f; acc1[nt][r] = 0.0f; }

  const uint8_t* wb = xf + w * 4096 + lane * 16;  // my frag base
  half8 bf[4];
#pragma unroll
  for (int nt = 0; nt < 4; ++nt)
    bf[nt] = *reinterpret_cast<const half8*>(wb + nt * 1024);

  for (int T = 0; T < 16; ++T) {
    half8 bn[4];
    if (T < 15) {
      const uint8_t* nb_ = wb + (T + 1) * 32768;
#pragma unroll
      for (int nt = 0; nt < 4; ++nt)
        bn[nt] = *reinterpret_cast<const half8*>(nb_ + nt * 1024);
    }
    // A-gen: w(s, t = T*128 + w*16 + h*8 + j)
    const float* kp = kb + T * 128 + w * 16 + h * 8;
    const float4 ka = *reinterpret_cast<const float4*>(kp);
    const float4 kc = *reinterpret_cast<const float4*>(kp + 4);
    const float kv8[8] = {ka.x, ka.y, ka.z, ka.w, kc.x, kc.y, kc.z, kc.w};
    half8 wa0, wa1;
#pragma unroll
    for (int j = 0; j < 8; ++j) {
      const float v0 = exp2f(fmaf(ga0, kv8[j], -gm0));
      const float v1 = exp2f(fmaf(ga1, kv8[j], -gm1));
      gden0 += v0; gden1 += v1;
      wa0[j] = (_Float16)v0;
      wa1[j] = (_Float16)v1;
    }
    __builtin_amdgcn_s_setprio(1);
#pragma unroll
    for (int nt = 0; nt < 4; ++nt) {
      acc0[nt] = __builtin_amdgcn_mfma_f32_32x32x16_f16(wa0, bf[nt], acc0[nt], 0, 0, 0);
      acc1[nt] = __builtin_amdgcn_mfma_f32_32x32x16_f16(wa1, bf[nt], acc1[nt], 0, 0, 0);
    }
    __builtin_amdgcn_s_setprio(0);
#pragma unroll
    for (int nt = 0; nt < 4; ++nt) bf[nt] = bn[nt];
  }

  // ---- combine: two halves in parallel (waves 0-3 -> comb[0], 4-7 -> comb[1])
  gden0 += __shfl_xor(gden0, 32, 64);
  gden1 += __shfl_xor(gden1, 32, 64);
  if (lane < 32) { dl[w * 64 + lane] = gden0; dl[w * 64 + 32 + lane] = gden1; }
#pragma unroll
  for (int p = 0; p < 4; ++p) {
    const int grp = w >> 2;       // 0 or 1
    if ((w & 3) == p) {
      float* cb = comb[grp];
#pragma unroll
      for (int nt = 0; nt < 4; ++nt)
#pragma unroll
        for (int r = 0; r < 16; ++r) {
          const int rr = (r & 3) + 8 * (r >> 2) + 4 * h;
          const int i0 = rr * 128 + nt * 32 + lm;
          const int i1 = (32 + rr) * 128 + nt * 32 + lm;
          if (p == 0) { cb[i0] = acc0[nt][r]; cb[i1] = acc1[nt][r]; }
          else        { cb[i0] += acc0[nt][r]; cb[i1] += acc1[nt][r]; }
        }
    }
    __syncthreads();
  }

  // ---- epilogue: sum halves, divide by denominator, store ----
  const int r = tid >> 3;          // 0..63
  const int cg = (tid & 7) * 16;   // 0..112
  float den = 0.0f;
#pragma unroll
  for (int q = 0; q < 8; ++q) den += dl[q * 64 + r];
  const float inv = 1.0f / den;
  float* orow = out + ((size_t)b * SS + s0 + r) * DD + cg;
#pragma unroll
  for (int q = 0; q < 4; ++q) {
    const float4 vA = *reinterpret_cast<const float4*>(&comb[0][r * 128 + cg + q * 4]);
    const float4 vB = *reinterpret_cast<const float4*>(&comb[1][r * 128 + cg + q * 4]);
    *reinterpret_cast<float4*>(orow + q * 4) =
        make_float4((vA.x + vB.x) * inv, (vA.y + vB.y) * inv,
                    (vA.z + vB.z) * inv, (vA.w + vB.w) * inv);
  }
}

// ---------------- fallback (ws too small): fp32 path ----------------
__global__ __launch_bounds__(256) void kminmax(const float* __restrict__ kvec,
                                               float* __restrict__ kmx,
                                               float* __restrict__ kmn) {
  const int b = blockIdx.x;
  const int tid = threadIdx.x;
  float mx = -1e30f, mn = 1e30f;
  for (int i = tid; i < SS; i += 256) {
    const float v = kvec[b * SS + i];
    mx = fmaxf(mx, v);
    mn = fminf(mn, v);
  }
#pragma unroll
  for (int off = 32; off > 0; off >>= 1) {
    mx = fmaxf(mx, __shfl_xor(mx, off, 64));
    mn = fminf(mn, __shfl_xor(mn, off, 64));
  }
  __shared__ float smx[4], smn[4];
  const int wid = tid >> 6, lane = tid & 63;
  if (lane == 0) { smx[wid] = mx; smn[wid] = mn; }
  __syncthreads();
  if (tid == 0) {
    kmx[b] = fmaxf(fmaxf(smx[0], smx[1]), fmaxf(smx[2], smx[3]));
    kmn[b] = fminf(fminf(smn[0], smn[1]), fminf(smn[2], smn[3]));
  }
}

__global__ __launch_bounds__(256) void attn_main(
    const float* __restrict__ X, const float* __restrict__ a2,
    const float* __restrict__ kvec, const float* __restrict__ kmx,
    const float* __restrict__ kmn, float* __restrict__ out) {
  __shared__ float xs[64 * DD];
  __shared__ float wt[64 * 32];
  __shared__ float denp[8 * 32];
  const int tid = threadIdx.x;
  const int tx = tid & 15;
  const int ty = (tid >> 4) & 3;
  const int tz = tid >> 6;
  const int b = blockIdx.y;
  const int s0 = blockIdx.x * 32;
  const int sg = tid & 31;
  const int tq = tid >> 5;
  const float ga = a2[b * SS + s0 + sg];
  const float gm = fmaxf(ga * kmx[b], ga * kmn[b]);
  float gden = 0.0f;
  float acc[8][8];
#pragma unroll
  for (int r = 0; r < 8; ++r)
#pragma unroll
    for (int c = 0; c < 8; ++c) acc[r][c] = 0.0f;
  const float* xb = X + (size_t)b * SS * DD;
  const float* kb = kvec + b * SS;
  for (int t0 = 0; t0 < SS; t0 += 64) {
    __syncthreads();
#pragma unroll
    for (int rnd = 0; rnd < 8; ++rnd) {
      const int idx = rnd * 1024 + tid * 4;
      *reinterpret_cast<float4*>(xs + idx) =
          *reinterpret_cast<const float4*>(xb + t0 * DD + idx);
    }
#pragma unroll
    for (int j = 0; j < 8; ++j) {
      const float kt = kb[t0 + tq * 8 + j];
      const float wv = exp2f(fmaf(ga, kt, -gm));
      wt[(tq * 8 + j) * 32 + sg] = wv;
      gden += wv;
    }
    __syncthreads();
#pragma unroll 4
    for (int ti = 0; ti < 16; ++ti) {
      const int tl = tz * 16 + ti;
      const float4 x0 = *reinterpret_cast<const float4*>(xs + tl * DD + tx * 8);
      const float4 x1 = *reinterpret_cast<const float4*>(xs + tl * DD + tx * 8 + 4);
      const float4 w0 = *reinterpret_cast<const float4*>(wt + tl * 32 + ty * 8);
      const float4 w1 = *reinterpret_cast<const float4*>(wt + tl * 32 + ty * 8 + 4);
      const float xr[8] = {x0.x, x0.y, x0.z, x0.w, x1.x, x1.y, x1.z, x1.w};
      const float wr[8] = {w0.x, w0.y, w0.z, w0.w, w1.x, w1.y, w1.z, w1.w};
#pragma unroll
      for (int r = 0; r < 8; ++r)
#pragma unroll
        for (int c = 0; c < 8; ++c) acc[r][c] = fmaf(wr[r], xr[c], acc[r][c]);
    }
  }
  __syncthreads();
  denp[tq * 32 + sg] = gden;
  for (int p = 1; p < 4; ++p) {
    __syncthreads();
    if (tz == p) {
#pragma unroll
      for (int r = 0; r < 8; ++r) {
        const int sl = ty * 8 + r;
        *reinterpret_cast<float4*>(xs + sl * DD + tx * 8) =
            make_float4(acc[r][0], acc[r][1], acc[r][2], acc[r][3]);
        *reinterpret_cast<float4*>(xs + sl * DD + tx * 8 + 4) =
            make_float4(acc[r][4], acc[r][5], acc[r][6], acc[r][7]);
      }
    }
    __syncthreads();
    if (tz == 0) {
#pragma unroll
      for (int r = 0; r < 8; ++r) {
        const int sl = ty * 8 + r;
        const float4 v0 = *reinterpret_cast<const float4*>(xs + sl * DD + tx * 8);
        const float4 v1 = *reinterpret_cast<const float4*>(xs + sl * DD + tx * 8 + 4);
        acc[r][0] += v0.x; acc[r][1] += v0.y; acc[r][2] += v0.z; acc[r][3] += v0.w;
        acc[r][4] += v1.x; acc[r][5] += v1.y; acc[r][6] += v1.z; acc[r][7] += v1.w;
      }
    }
  }
  if (tz == 0) {
#pragma unroll
    for (int r = 0; r < 8; ++r) {
      const int sl = ty * 8 + r;
      float den = 0.0f;
#pragma unroll
      for (int q = 0; q < 8; ++q) den += denp[q * 32 + sl];
      const float inv = 1.0f / den;
      float* orow = out + ((size_t)b * SS + s0 + sl) * DD + tx * 8;
      *reinterpret_cast<float4*>(orow) =
          make_float4(acc[r][0] * inv, acc[r][1] * inv, acc[r][2] * inv, acc[r][3] * inv);
      *reinterpret_cast<float4*>(orow + 4) =
          make_float4(acc[r][4] * inv, acc[r][5] * inv, acc[r][6] * inv, acc[r][7] * inv);
    }
  }
}

extern "C" void kernel_launch(void* const* d_in, const int* in_sizes, int n_in,
                              void* d_out, int out_size, void* d_ws, size_t ws_size,
                              hipStream_t stream) {
  const float* X = (const float*)d_in[0];
  const float* rotp = (const float*)d_in[1];
  const float* entp = (const float*)d_in[2];
  float* out = (float*)d_out;
  uint8_t* ws = (uint8_t*)d_ws;

  if (ws_size >= WS_NEED) {
    prep<<<512, 256, 0, stream>>>(X, rotp, entp, ws, 1);
    attn_mfma<<<256, 512, 0, stream>>>((const uint8_t*)ws, out);
  } else {
    float* a2 = (float*)(ws + WS_A2);
    float* kv = (float*)(ws + WS_KV);
    float* kmxp = (float*)(ws + WS_KMX);
    float* kmnp = (float*)(ws + WS_KMN);
    prep<<<512, 256, 0, stream>>>(X, rotp, entp, ws, 0);
    kminmax<<<NB, 256, 0, stream>>>(kv, kmxp, kmnp);
    attn_main<<<dim3(SS / 32, NB), 256, 0, stream>>>(X, a2, kv, kmxp, kmnp, out);
  }
}

// Round 13
// 28.818 us; speedup vs baseline: 3.1080x; 1.0974x over previous
//
#include <hip/hip_runtime.h>
#include <cstddef>
#include <cstdint>

#define SS 2048
#define DD 128
#define NB 8

typedef _Float16 half8 __attribute__((ext_vector_type(8)));
typedef __fp16 fp16x2 __attribute__((ext_vector_type(2)));
typedef __attribute__((ext_vector_type(16))) float f32x16;

#if __has_builtin(__builtin_amdgcn_exp2f)
#define EXP2F(x) __builtin_amdgcn_exp2f(x)
#else
#define EXP2F(x) exp2f(x)
#endif

// ---- workspace layout (bytes) ----
#define WS_A2   0                      // NB*SS f32 (pre-folded a*log2e/sqrt(d))
#define WS_KV   (NB*SS*4)              // NB*SS f32
#define WS_XF   (2*NB*SS*4)            // 131072: fp16 fragment-major X^T
#define BATCH_B (SS*DD*2)              // 512 KiB per batch
#define WS_NEED (size_t)(WS_XF + (size_t)NB*BATCH_B)   // ~4.33 MB
// fallback-only scratch (fits in WS_XF area)
#define WS_KMX  (WS_XF)
#define WS_KMN  (WS_XF + 128)

// Fragment-major layout for X^T fp16, per batch:
//   element X[t][d]:  T=t>>7, t'=t&127, w=t'>>4, hh=(t'>>3)&1, j=t'&7,
//                     nt=d>>5, lm=d&31, lane=lm+(hh<<5)
//   byte = (T*8+w)*4096 + nt*1024 + lane*16 + j*2
// => wave w's B-frag (T,nt) is ONE contiguous 1 KiB block (dwordx4/lane).

// ---------------- Kernel 1: fused projections + X->fp16 fragment store -----
// Block (b, rc) covers 32 t-rows x 128 d. Phase 1: coalesced read + projection
// reduce + fp16 into LDS [d][t31] (row stride 80 B). Phase 2: ds_read_b128 +
// fully-coalesced global_store_dwordx4.
__global__ __launch_bounds__(256) void prep(
    const float* __restrict__ X, const float* __restrict__ rotp,
    const float* __restrict__ entp, uint8_t* __restrict__ ws, int do_x) {
  __shared__ __align__(16) uint8_t lbuf[128 * 80];  // 10 KiB
  const int blk = blockIdx.x;
  const int b = blk & 7;
  const int rc = blk >> 3;
  const int tid = threadIdx.x;
  const int d4 = (tid & 31) * 4;
  float* a2out = (float*)(ws + WS_A2);
  float* kout = (float*)(ws + WS_KV);

  const float4 f0 = *reinterpret_cast<const float4*>(rotp + d4 * 3);
  const float4 f1 = *reinterpret_cast<const float4*>(rotp + d4 * 3 + 4);
  const float4 f2 = *reinterpret_cast<const float4*>(rotp + d4 * 3 + 8);
  const float rs0 = f0.x + f0.y + f0.z;
  const float rs1 = f0.w + f1.x + f1.y;
  const float rs2 = f1.z + f1.w + f2.x;
  const float rs3 = f2.y + f2.z + f2.w;
  const float4 e4 = *reinterpret_cast<const float4*>(entp + d4);

#pragma unroll
  for (int rnd = 0; rnd < 4; ++rnd) {
    const int t31 = rnd * 8 + (tid >> 5);           // 0..31 within block
    const int tg = rc * 32 + t31;                   // t within batch
    const float4 xv =
        *reinterpret_cast<const float4*>(X + ((size_t)b * SS + tg) * DD + d4);
    float av = xv.x * rs0 + xv.y * rs1 + xv.z * rs2 + xv.w * rs3;
    float kv = xv.x * e4.x + xv.y * e4.y + xv.z * e4.z + xv.w * e4.w;
#pragma unroll
    for (int off = 16; off > 0; off >>= 1) {
      av += __shfl_xor(av, off, 64);
      kv += __shfl_xor(kv, off, 64);
    }
    if ((tid & 31) == 0) {
      a2out[b * SS + tg] = av * (0.08838834764831845f * 1.4426950408889634f);
      kout[b * SS + tg] = kv;
    }
    if (do_x) {
      const float vv[4] = {xv.x, xv.y, xv.z, xv.w};
#pragma unroll
      for (int i = 0; i < 4; ++i)
        *reinterpret_cast<_Float16*>(lbuf + (d4 + i) * 80 + t31 * 2) =
            (_Float16)vv[i];
    }
  }

  if (do_x) {
    __syncthreads();
    const int T = rc >> 2;
    const int wfb = (rc & 3) * 2;
    uint8_t* outb = ws + WS_XF + (size_t)b * BATCH_B + (T * 8 + wfb) * 4096;
    const int nt = tid >> 6;
    const int lane = tid & 63;
    const int hh = lane >> 5;
    const int d = nt * 32 + (lane & 31);
#pragma unroll
    for (int wfl = 0; wfl < 2; ++wfl) {
      const half8 v = *reinterpret_cast<const half8*>(
          lbuf + d * 80 + (wfl * 16 + hh * 8) * 2);
      *reinterpret_cast<half8*>(outb + wfl * 4096 + nt * 1024 + lane * 16) = v;
    }
  }
}

// ---------------- Kernel 2: MFMA softmax-weighted PV, LDS-free main loop ---
// 256 blocks: b = blk&7 (XCD affinity), s0 = (blk>>3)*64. 8 waves = 8
// disjoint 16-t k-slices per 128-t tile; B-frags loaded global->VGPR
// (coalesced 1KB/wave), 1-deep prefetch of BOTH B-frags and k-vectors,
// bare v_exp_f32 + packed f32->f16 RTZ cvt, NO barriers in the main loop.
__global__ __launch_bounds__(512, 2) void attn_mfma(
    const uint8_t* __restrict__ ws, float* __restrict__ out) {
  __shared__ float comb[2][64 * 128];  // 64 KiB
  __shared__ float dl[8 * 64];
  __shared__ float smx[8], smn[8];
  const int tid = threadIdx.x;
  const int w = tid >> 6;
  const int lane = tid & 63;
  const int lm = lane & 31;
  const int h = lane >> 5;
  const int blk = blockIdx.x;
  const int b = blk & 7;
  const int s0 = (blk >> 3) * 64;

  const float* a2 = (const float*)(ws + WS_A2) + b * SS;
  const float* kb = (const float*)(ws + WS_KV) + b * SS;
  const uint8_t* xf = ws + WS_XF + (size_t)b * BATCH_B;

  // per-batch kmax/kmin (512 thr x 4)
  const float4 k4 = *reinterpret_cast<const float4*>(kb + tid * 4);
  float mx = fmaxf(fmaxf(k4.x, k4.y), fmaxf(k4.z, k4.w));
  float mn = fminf(fminf(k4.x, k4.y), fminf(k4.z, k4.w));
#pragma unroll
  for (int off = 32; off > 0; off >>= 1) {
    mx = fmaxf(mx, __shfl_xor(mx, off, 64));
    mn = fminf(mn, __shfl_xor(mn, off, 64));
  }
  if (lane == 0) { smx[w] = mx; smn[w] = mn; }
  const float ga0 = a2[s0 + lm];
  const float ga1 = a2[s0 + 32 + lm];
  __syncthreads();
  mx = smx[0]; mn = smn[0];
#pragma unroll
  for (int q = 1; q < 8; ++q) { mx = fmaxf(mx, smx[q]); mn = fminf(mn, smn[q]); }
  const float gm0 = fmaxf(ga0 * mx, ga0 * mn);
  const float gm1 = fmaxf(ga1 * mx, ga1 * mn);
  float gden0 = 0.0f, gden1 = 0.0f;

  f32x16 acc0[4], acc1[4];
#pragma unroll
  for (int nt = 0; nt < 4; ++nt)
#pragma unroll
    for (int r = 0; r < 16; ++r) { acc0[nt][r] = 0.0f; acc1[nt][r] = 0.0f; }

  const uint8_t* wb = xf + w * 4096 + lane * 16;  // my frag base
  const float* kp0 = kb + w * 16 + h * 8;

  half8 bf[4];
#pragma unroll
  for (int nt = 0; nt < 4; ++nt)
    bf[nt] = *reinterpret_cast<const half8*>(wb + nt * 1024);
  float4 kcur0 = *reinterpret_cast<const float4*>(kp0);
  float4 kcur1 = *reinterpret_cast<const float4*>(kp0 + 4);

  for (int T = 0; T < 16; ++T) {
    half8 bn[4];
    float4 knx0, knx1;
    if (T < 15) {
      const uint8_t* nb_ = wb + (T + 1) * 32768;
#pragma unroll
      for (int nt = 0; nt < 4; ++nt)
        bn[nt] = *reinterpret_cast<const half8*>(nb_ + nt * 1024);
      knx0 = *reinterpret_cast<const float4*>(kp0 + (T + 1) * 128);
      knx1 = *reinterpret_cast<const float4*>(kp0 + (T + 1) * 128 + 4);
    }
    // A-gen from prefetched k: w(s, t = T*128 + w*16 + h*8 + j)
    const float kv8[8] = {kcur0.x, kcur0.y, kcur0.z, kcur0.w,
                          kcur1.x, kcur1.y, kcur1.z, kcur1.w};
    float e0[8], e1[8];
#pragma unroll
    for (int j = 0; j < 8; ++j) {
      e0[j] = EXP2F(fmaf(ga0, kv8[j], -gm0));
      e1[j] = EXP2F(fmaf(ga1, kv8[j], -gm1));
      gden0 += e0[j]; gden1 += e1[j];
    }
    union { half8 v; fp16x2 p[4]; } wa0, wa1;
#pragma unroll
    for (int q = 0; q < 4; ++q) {
      wa0.p[q] = __builtin_amdgcn_cvt_pkrtz(e0[2 * q], e0[2 * q + 1]);
      wa1.p[q] = __builtin_amdgcn_cvt_pkrtz(e1[2 * q], e1[2 * q + 1]);
    }
    __builtin_amdgcn_s_setprio(1);
#pragma unroll
    for (int nt = 0; nt < 4; ++nt) {
      acc0[nt] = __builtin_amdgcn_mfma_f32_32x32x16_f16(wa0.v, bf[nt], acc0[nt], 0, 0, 0);
      acc1[nt] = __builtin_amdgcn_mfma_f32_32x32x16_f16(wa1.v, bf[nt], acc1[nt], 0, 0, 0);
    }
    __builtin_amdgcn_s_setprio(0);
#pragma unroll
    for (int nt = 0; nt < 4; ++nt) bf[nt] = bn[nt];
    kcur0 = knx0; kcur1 = knx1;
  }

  // ---- combine: two halves in parallel (waves 0-3 -> comb[0], 4-7 -> comb[1])
  gden0 += __shfl_xor(gden0, 32, 64);
  gden1 += __shfl_xor(gden1, 32, 64);
  if (lane < 32) { dl[w * 64 + lane] = gden0; dl[w * 64 + 32 + lane] = gden1; }
#pragma unroll
  for (int p = 0; p < 4; ++p) {
    const int grp = w >> 2;       // 0 or 1
    if ((w & 3) == p) {
      float* cb = comb[grp];
#pragma unroll
      for (int nt = 0; nt < 4; ++nt)
#pragma unroll
        for (int r = 0; r < 16; ++r) {
          const int rr = (r & 3) + 8 * (r >> 2) + 4 * h;
          const int i0 = rr * 128 + nt * 32 + lm;
          const int i1 = (32 + rr) * 128 + nt * 32 + lm;
          if (p == 0) { cb[i0] = acc0[nt][r]; cb[i1] = acc1[nt][r]; }
          else        { cb[i0] += acc0[nt][r]; cb[i1] += acc1[nt][r]; }
        }
    }
    __syncthreads();
  }

  // ---- epilogue: sum halves, divide by denominator, store ----
  const int r = tid >> 3;          // 0..63
  const int cg = (tid & 7) * 16;   // 0..112
  float den = 0.0f;
#pragma unroll
  for (int q = 0; q < 8; ++q) den += dl[q * 64 + r];
  const float inv = 1.0f / den;
  float* orow = out + ((size_t)b * SS + s0 + r) * DD + cg;
#pragma unroll
  for (int q = 0; q < 4; ++q) {
    const float4 vA = *reinterpret_cast<const float4*>(&comb[0][r * 128 + cg + q * 4]);
    const float4 vB = *reinterpret_cast<const float4*>(&comb[1][r * 128 + cg + q * 4]);
    *reinterpret_cast<float4*>(orow + q * 4) =
        make_float4((vA.x + vB.x) * inv, (vA.y + vB.y) * inv,
                    (vA.z + vB.z) * inv, (vA.w + vB.w) * inv);
  }
}

// ---------------- fallback (ws too small): fp32 path ----------------
__global__ __launch_bounds__(256) void kminmax(const float* __restrict__ kvec,
                                               float* __restrict__ kmx,
                                               float* __restrict__ kmn) {
  const int b = blockIdx.x;
  const int tid = threadIdx.x;
  float mx = -1e30f, mn = 1e30f;
  for (int i = tid; i < SS; i += 256) {
    const float v = kvec[b * SS + i];
    mx = fmaxf(mx, v);
    mn = fminf(mn, v);
  }
#pragma unroll
  for (int off = 32; off > 0; off >>= 1) {
    mx = fmaxf(mx, __shfl_xor(mx, off, 64));
    mn = fminf(mn, __shfl_xor(mn, off, 64));
  }
  __shared__ float smx[4], smn[4];
  const int wid = tid >> 6, lane = tid & 63;
  if (lane == 0) { smx[wid] = mx; smn[wid] = mn; }
  __syncthreads();
  if (tid == 0) {
    kmx[b] = fmaxf(fmaxf(smx[0], smx[1]), fmaxf(smx[2], smx[3]));
    kmn[b] = fminf(fminf(smn[0], smn[1]), fminf(smn[2], smn[3]));
  }
}

__global__ __launch_bounds__(256) void attn_main(
    const float* __restrict__ X, const float* __restrict__ a2,
    const float* __restrict__ kvec, const float* __restrict__ kmx,
    const float* __restrict__ kmn, float* __restrict__ out) {
  __shared__ float xs[64 * DD];
  __shared__ float wt[64 * 32];
  __shared__ float denp[8 * 32];
  const int tid = threadIdx.x;
  const int tx = tid & 15;
  const int ty = (tid >> 4) & 3;
  const int tz = tid >> 6;
  const int b = blockIdx.y;
  const int s0 = blockIdx.x * 32;
  const int sg = tid & 31;
  const int tq = tid >> 5;
  const float ga = a2[b * SS + s0 + sg];
  const float gm = fmaxf(ga * kmx[b], ga * kmn[b]);
  float gden = 0.0f;
  float acc[8][8];
#pragma unroll
  for (int r = 0; r < 8; ++r)
#pragma unroll
    for (int c = 0; c < 8; ++c) acc[r][c] = 0.0f;
  const float* xb = X + (size_t)b * SS * DD;
  const float* kb = kvec + b * SS;
  for (int t0 = 0; t0 < SS; t0 += 64) {
    __syncthreads();
#pragma unroll
    for (int rnd = 0; rnd < 8; ++rnd) {
      const int idx = rnd * 1024 + tid * 4;
      *reinterpret_cast<float4*>(xs + idx) =
          *reinterpret_cast<const float4*>(xb + t0 * DD + idx);
    }
#pragma unroll
    for (int j = 0; j < 8; ++j) {
      const float kt = kb[t0 + tq * 8 + j];
      const float wv = exp2f(fmaf(ga, kt, -gm));
      wt[(tq * 8 + j) * 32 + sg] = wv;
      gden += wv;
    }
    __syncthreads();
#pragma unroll 4
    for (int ti = 0; ti < 16; ++ti) {
      const int tl = tz * 16 + ti;
      const float4 x0 = *reinterpret_cast<const float4*>(xs + tl * DD + tx * 8);
      const float4 x1 = *reinterpret_cast<const float4*>(xs + tl * DD + tx * 8 + 4);
      const float4 w0 = *reinterpret_cast<const float4*>(wt + tl * 32 + ty * 8);
      const float4 w1 = *reinterpret_cast<const float4*>(wt + tl * 32 + ty * 8 + 4);
      const float xr[8] = {x0.x, x0.y, x0.z, x0.w, x1.x, x1.y, x1.z, x1.w};
      const float wr[8] = {w0.x, w0.y, w0.z, w0.w, w1.x, w1.y, w1.z, w1.w};
#pragma unroll
      for (int r = 0; r < 8; ++r)
#pragma unroll
        for (int c = 0; c < 8; ++c) acc[r][c] = fmaf(wr[r], xr[c], acc[r][c]);
    }
  }
  __syncthreads();
  denp[tq * 32 + sg] = gden;
  for (int p = 1; p < 4; ++p) {
    __syncthreads();
    if (tz == p) {
#pragma unroll
      for (int r = 0; r < 8; ++r) {
        const int sl = ty * 8 + r;
        *reinterpret_cast<float4*>(xs + sl * DD + tx * 8) =
            make_float4(acc[r][0], acc[r][1], acc[r][2], acc[r][3]);
        *reinterpret_cast<float4*>(xs + sl * DD + tx * 8 + 4) =
            make_float4(acc[r][4], acc[r][5], acc[r][6], acc[r][7]);
      }
    }
    __syncthreads();
    if (tz == 0) {
#pragma unroll
      for (int r = 0; r < 8; ++r) {
        const int sl = ty * 8 + r;
        const float4 v0 = *reinterpret_cast<const float4*>(xs + sl * DD + tx * 8);
        const float4 v1 = *reinterpret_cast<const float4*>(xs + sl * DD + tx * 8 + 4);
        acc[r][0] += v0.x; acc[r][1] += v0.y; acc[r][2] += v0.z; acc[r][3] += v0.w;
        acc[r][4] += v1.x; acc[r][5] += v1.y; acc[r][6] += v1.z; acc[r][7] += v1.w;
      }
    }
  }
  if (tz == 0) {
#pragma unroll
    for (int r = 0; r < 8; ++r) {
      const int sl = ty * 8 + r;
      float den = 0.0f;
#pragma unroll
      for (int q = 0; q < 8; ++q) den += denp[q * 32 + sl];
      const float inv = 1.0f / den;
      float* orow = out + ((size_t)b * SS + s0 + sl) * DD + tx * 8;
      *reinterpret_cast<float4*>(orow) =
          make_float4(acc[r][0] * inv, acc[r][1] * inv, acc[r][2] * inv, acc[r][3] * inv);
      *reinterpret_cast<float4*>(orow + 4) =
          make_float4(acc[r][4] * inv, acc[r][5] * inv, acc[r][6] * inv, acc[r][7] * inv);
    }
  }
}

extern "C" void kernel_launch(void* const* d_in, const int* in_sizes, int n_in,
                              void* d_out, int out_size, void* d_ws, size_t ws_size,
                              hipStream_t stream) {
  const float* X = (const float*)d_in[0];
  const float* rotp = (const float*)d_in[1];
  const float* entp = (const float*)d_in[2];
  float* out = (float*)d_out;
  uint8_t* ws = (uint8_t*)d_ws;

  if (ws_size >= WS_NEED) {
    prep<<<512, 256, 0, stream>>>(X, rotp, entp, ws, 1);
    attn_mfma<<<256, 512, 0, stream>>>((const uint8_t*)ws, out);
  } else {
    float* a2 = (float*)(ws + WS_A2);
    float* kv = (float*)(ws + WS_KV);
    float* kmxp = (float*)(ws + WS_KMX);
    float* kmnp = (float*)(ws + WS_KMN);
    prep<<<512, 256, 0, stream>>>(X, rotp, entp, ws, 0);
    kminmax<<<NB, 256, 0, stream>>>(kv, kmxp, kmnp);
    attn_main<<<dim3(SS / 32, NB), 256, 0, stream>>>(X, a2, kv, kmxp, kmnp, out);
  }
}

// Round 14
// 28.460 us; speedup vs baseline: 3.1471x; 1.0126x over previous
//
#include <hip/hip_runtime.h>
#include <cstddef>
#include <cstdint>

#define SS 2048
#define DD 128
#define NB 8

typedef _Float16 half8 __attribute__((ext_vector_type(8)));
typedef __fp16 fp16x2 __attribute__((ext_vector_type(2)));
typedef __attribute__((ext_vector_type(16))) float f32x16;

#if __has_builtin(__builtin_amdgcn_exp2f)
#define EXP2F(x) __builtin_amdgcn_exp2f(x)
#else
#define EXP2F(x) exp2f(x)
#endif

// ---- workspace layout (bytes) ----
#define WS_A2   0                      // NB*SS f32 (pre-folded a*log2e/sqrt(d))
#define WS_KV   (NB*SS*4)              // NB*SS f32
#define WS_XF   (2*NB*SS*4)            // 131072: fp16 fragment-major X^T
#define BATCH_B (SS*DD*2)              // 512 KiB per batch
#define WS_NEED (size_t)(WS_XF + (size_t)NB*BATCH_B)   // ~4.33 MB
// fallback-only scratch (fits in WS_XF area)
#define WS_KMX  (WS_XF)
#define WS_KMN  (WS_XF + 128)

// Fragment-major layout for X^T fp16, per batch:
//   element X[t][d]:  T=t>>7, t'=t&127, w=t'>>4, hh=(t'>>3)&1, j=t'&7,
//                     nt=d>>5, lm=d&31, lane=lm+(hh<<5)
//   byte = (T*8+w)*4096 + nt*1024 + lane*16 + j*2
// => wave w's B-frag (T,nt) is ONE contiguous 1 KiB block (dwordx4/lane).

// ---------------- Kernel 1: fused projections + X->fp16 fragment store -----
__global__ __launch_bounds__(256) void prep(
    const float* __restrict__ X, const float* __restrict__ rotp,
    const float* __restrict__ entp, uint8_t* __restrict__ ws, int do_x) {
  __shared__ __align__(16) uint8_t lbuf[128 * 80];  // 10 KiB
  const int blk = blockIdx.x;
  const int b = blk & 7;
  const int rc = blk >> 3;
  const int tid = threadIdx.x;
  const int d4 = (tid & 31) * 4;
  float* a2out = (float*)(ws + WS_A2);
  float* kout = (float*)(ws + WS_KV);

  const float4 f0 = *reinterpret_cast<const float4*>(rotp + d4 * 3);
  const float4 f1 = *reinterpret_cast<const float4*>(rotp + d4 * 3 + 4);
  const float4 f2 = *reinterpret_cast<const float4*>(rotp + d4 * 3 + 8);
  const float rs0 = f0.x + f0.y + f0.z;
  const float rs1 = f0.w + f1.x + f1.y;
  const float rs2 = f1.z + f1.w + f2.x;
  const float rs3 = f2.y + f2.z + f2.w;
  const float4 e4 = *reinterpret_cast<const float4*>(entp + d4);

#pragma unroll
  for (int rnd = 0; rnd < 4; ++rnd) {
    const int t31 = rnd * 8 + (tid >> 5);           // 0..31 within block
    const int tg = rc * 32 + t31;                   // t within batch
    const float4 xv =
        *reinterpret_cast<const float4*>(X + ((size_t)b * SS + tg) * DD + d4);
    float av = xv.x * rs0 + xv.y * rs1 + xv.z * rs2 + xv.w * rs3;
    float kv = xv.x * e4.x + xv.y * e4.y + xv.z * e4.z + xv.w * e4.w;
#pragma unroll
    for (int off = 16; off > 0; off >>= 1) {
      av += __shfl_xor(av, off, 64);
      kv += __shfl_xor(kv, off, 64);
    }
    if ((tid & 31) == 0) {
      a2out[b * SS + tg] = av * (0.08838834764831845f * 1.4426950408889634f);
      kout[b * SS + tg] = kv;
    }
    if (do_x) {
      const float vv[4] = {xv.x, xv.y, xv.z, xv.w};
#pragma unroll
      for (int i = 0; i < 4; ++i)
        *reinterpret_cast<_Float16*>(lbuf + (d4 + i) * 80 + t31 * 2) =
            (_Float16)vv[i];
    }
  }

  if (do_x) {
    __syncthreads();
    const int T = rc >> 2;
    const int wfb = (rc & 3) * 2;
    uint8_t* outb = ws + WS_XF + (size_t)b * BATCH_B + (T * 8 + wfb) * 4096;
    const int nt = tid >> 6;
    const int lane = tid & 63;
    const int hh = lane >> 5;
    const int d = nt * 32 + (lane & 31);
#pragma unroll
    for (int wfl = 0; wfl < 2; ++wfl) {
      const half8 v = *reinterpret_cast<const half8*>(
          lbuf + d * 80 + (wfl * 16 + hh * 8) * 2);
      *reinterpret_cast<half8*>(outb + wfl * 4096 + nt * 1024 + lane * 16) = v;
    }
  }
}

// ---------------- Kernel 2: MFMA softmax-weighted PV, LDS-free main loop ---
// 512 blocks: b = blk&7 (XCD affinity), s0 = (blk>>3)*32 -> 2 blocks/CU,
// 4 waves/SIMD. 8 waves = 8 disjoint 16-t k-slices per 128-t tile; one ga
// per wave (acc = 64 regs). B-frags global->VGPR, 1-deep prefetch, no
// main-loop barriers.
__global__ __launch_bounds__(512, 4) void attn_mfma(
    const uint8_t* __restrict__ ws, float* __restrict__ out) {
  __shared__ float comb[2][32 * 128];  // 32 KiB
  __shared__ float dl[8 * 32];
  __shared__ float smx[8], smn[8];
  const int tid = threadIdx.x;
  const int w = tid >> 6;
  const int lane = tid & 63;
  const int lm = lane & 31;
  const int h = lane >> 5;
  const int blk = blockIdx.x;
  const int b = blk & 7;
  const int s0 = (blk >> 3) * 32;

  const float* a2 = (const float*)(ws + WS_A2) + b * SS;
  const float* kb = (const float*)(ws + WS_KV) + b * SS;
  const uint8_t* xf = ws + WS_XF + (size_t)b * BATCH_B;

  // per-batch kmax/kmin (512 thr x 4)
  const float4 k4 = *reinterpret_cast<const float4*>(kb + tid * 4);
  float mx = fmaxf(fmaxf(k4.x, k4.y), fmaxf(k4.z, k4.w));
  float mn = fminf(fminf(k4.x, k4.y), fminf(k4.z, k4.w));
#pragma unroll
  for (int off = 32; off > 0; off >>= 1) {
    mx = fmaxf(mx, __shfl_xor(mx, off, 64));
    mn = fminf(mn, __shfl_xor(mn, off, 64));
  }
  if (lane == 0) { smx[w] = mx; smn[w] = mn; }
  const float ga = a2[s0 + lm];
  __syncthreads();
  mx = smx[0]; mn = smn[0];
#pragma unroll
  for (int q = 1; q < 8; ++q) { mx = fmaxf(mx, smx[q]); mn = fminf(mn, smn[q]); }
  const float gm = fmaxf(ga * mx, ga * mn);
  float gden = 0.0f;

  f32x16 acc[4];
#pragma unroll
  for (int nt = 0; nt < 4; ++nt)
#pragma unroll
    for (int r = 0; r < 16; ++r) acc[nt][r] = 0.0f;

  const uint8_t* wb = xf + w * 4096 + lane * 16;  // my frag base
  const float* kp0 = kb + w * 16 + h * 8;

  half8 bf[4];
#pragma unroll
  for (int nt = 0; nt < 4; ++nt)
    bf[nt] = *reinterpret_cast<const half8*>(wb + nt * 1024);

  for (int T = 0; T < 16; ++T) {
    half8 bn[4];
    if (T < 15) {
      const uint8_t* nb_ = wb + (T + 1) * 32768;
#pragma unroll
      for (int nt = 0; nt < 4; ++nt)
        bn[nt] = *reinterpret_cast<const half8*>(nb_ + nt * 1024);
    }
    // A-gen: w(s=lm, t = T*128 + w*16 + h*8 + j)
    const float* kp = kp0 + T * 128;
    const float4 ka = *reinterpret_cast<const float4*>(kp);
    const float4 kc = *reinterpret_cast<const float4*>(kp + 4);
    const float kv8[8] = {ka.x, ka.y, ka.z, ka.w, kc.x, kc.y, kc.z, kc.w};
    float e0[8];
#pragma unroll
    for (int j = 0; j < 8; ++j) {
      e0[j] = EXP2F(fmaf(ga, kv8[j], -gm));
      gden += e0[j];
    }
    union { half8 v; fp16x2 p[4]; } wa;
#pragma unroll
    for (int q = 0; q < 4; ++q)
      wa.p[q] = __builtin_amdgcn_cvt_pkrtz(e0[2 * q], e0[2 * q + 1]);
    __builtin_amdgcn_s_setprio(1);
#pragma unroll
    for (int nt = 0; nt < 4; ++nt)
      acc[nt] = __builtin_amdgcn_mfma_f32_32x32x16_f16(wa.v, bf[nt], acc[nt], 0, 0, 0);
    __builtin_amdgcn_s_setprio(0);
#pragma unroll
    for (int nt = 0; nt < 4; ++nt) bf[nt] = bn[nt];
  }

  // ---- combine: waves 0-3 -> comb[0], 4-7 -> comb[1], 4 phases ----
  gden += __shfl_xor(gden, 32, 64);
  if (lane < 32) dl[w * 32 + lane] = gden;
#pragma unroll
  for (int p = 0; p < 4; ++p) {
    const int grp = w >> 2;       // 0 or 1
    if ((w & 3) == p) {
      float* cb = comb[grp];
#pragma unroll
      for (int nt = 0; nt < 4; ++nt)
#pragma unroll
        for (int r = 0; r < 16; ++r) {
          const int rr = (r & 3) + 8 * (r >> 2) + 4 * h;
          const int i0 = rr * 128 + nt * 32 + lm;
          if (p == 0) cb[i0] = acc[nt][r];
          else        cb[i0] += acc[nt][r];
        }
    }
    __syncthreads();
  }

  // ---- epilogue: sum copies, divide by denominator, store ----
  const int r = tid >> 4;          // 0..31
  const int cg = (tid & 15) * 8;   // 0..120
  float den = 0.0f;
#pragma unroll
  for (int q = 0; q < 8; ++q) den += dl[q * 32 + r];
  const float inv = 1.0f / den;
  float* orow = out + ((size_t)b * SS + s0 + r) * DD + cg;
#pragma unroll
  for (int q = 0; q < 2; ++q) {
    const float4 vA = *reinterpret_cast<const float4*>(&comb[0][r * 128 + cg + q * 4]);
    const float4 vB = *reinterpret_cast<const float4*>(&comb[1][r * 128 + cg + q * 4]);
    *reinterpret_cast<float4*>(orow + q * 4) =
        make_float4((vA.x + vB.x) * inv, (vA.y + vB.y) * inv,
                    (vA.z + vB.z) * inv, (vA.w + vB.w) * inv);
  }
}

// ---------------- fallback (ws too small): fp32 path ----------------
__global__ __launch_bounds__(256) void kminmax(const float* __restrict__ kvec,
                                               float* __restrict__ kmx,
                                               float* __restrict__ kmn) {
  const int b = blockIdx.x;
  const int tid = threadIdx.x;
  float mx = -1e30f, mn = 1e30f;
  for (int i = tid; i < SS; i += 256) {
    const float v = kvec[b * SS + i];
    mx = fmaxf(mx, v);
    mn = fminf(mn, v);
  }
#pragma unroll
  for (int off = 32; off > 0; off >>= 1) {
    mx = fmaxf(mx, __shfl_xor(mx, off, 64));
    mn = fminf(mn, __shfl_xor(mn, off, 64));
  }
  __shared__ float smx[4], smn[4];
  const int wid = tid >> 6, lane = tid & 63;
  if (lane == 0) { smx[wid] = mx; smn[wid] = mn; }
  __syncthreads();
  if (tid == 0) {
    kmx[b] = fmaxf(fmaxf(smx[0], smx[1]), fmaxf(smx[2], smx[3]));
    kmn[b] = fminf(fminf(smn[0], smn[1]), fminf(smn[2], smn[3]));
  }
}

__global__ __launch_bounds__(256) void attn_main(
    const float* __restrict__ X, const float* __restrict__ a2,
    const float* __restrict__ kvec, const float* __restrict__ kmx,
    const float* __restrict__ kmn, float* __restrict__ out) {
  __shared__ float xs[64 * DD];
  __shared__ float wt[64 * 32];
  __shared__ float denp[8 * 32];
  const int tid = threadIdx.x;
  const int tx = tid & 15;
  const int ty = (tid >> 4) & 3;
  const int tz = tid >> 6;
  const int b = blockIdx.y;
  const int s0 = blockIdx.x * 32;
  const int sg = tid & 31;
  const int tq = tid >> 5;
  const float ga = a2[b * SS + s0 + sg];
  const float gm = fmaxf(ga * kmx[b], ga * kmn[b]);
  float gden = 0.0f;
  float acc[8][8];
#pragma unroll
  for (int r = 0; r < 8; ++r)
#pragma unroll
    for (int c = 0; c < 8; ++c) acc[r][c] = 0.0f;
  const float* xb = X + (size_t)b * SS * DD;
  const float* kb = kvec + b * SS;
  for (int t0 = 0; t0 < SS; t0 += 64) {
    __syncthreads();
#pragma unroll
    for (int rnd = 0; rnd < 8; ++rnd) {
      const int idx = rnd * 1024 + tid * 4;
      *reinterpret_cast<float4*>(xs + idx) =
          *reinterpret_cast<const float4*>(xb + t0 * DD + idx);
    }
#pragma unroll
    for (int j = 0; j < 8; ++j) {
      const float kt = kb[t0 + tq * 8 + j];
      const float wv = exp2f(fmaf(ga, kt, -gm));
      wt[(tq * 8 + j) * 32 + sg] = wv;
      gden += wv;
    }
    __syncthreads();
#pragma unroll 4
    for (int ti = 0; ti < 16; ++ti) {
      const int tl = tz * 16 + ti;
      const float4 x0 = *reinterpret_cast<const float4*>(xs + tl * DD + tx * 8);
      const float4 x1 = *reinterpret_cast<const float4*>(xs + tl * DD + tx * 8 + 4);
      const float4 w0 = *reinterpret_cast<const float4*>(wt + tl * 32 + ty * 8);
      const float4 w1 = *reinterpret_cast<const float4*>(wt + tl * 32 + ty * 8 + 4);
      const float xr[8] = {x0.x, x0.y, x0.z, x0.w, x1.x, x1.y, x1.z, x1.w};
      const float wr[8] = {w0.x, w0.y, w0.z, w0.w, w1.x, w1.y, w1.z, w1.w};
#pragma unroll
      for (int r = 0; r < 8; ++r)
#pragma unroll
        for (int c = 0; c < 8; ++c) acc[r][c] = fmaf(wr[r], xr[c], acc[r][c]);
    }
  }
  __syncthreads();
  denp[tq * 32 + sg] = gden;
  for (int p = 1; p < 4; ++p) {
    __syncthreads();
    if (tz == p) {
#pragma unroll
      for (int r = 0; r < 8; ++r) {
        const int sl = ty * 8 + r;
        *reinterpret_cast<float4*>(xs + sl * DD + tx * 8) =
            make_float4(acc[r][0], acc[r][1], acc[r][2], acc[r][3]);
        *reinterpret_cast<float4*>(xs + sl * DD + tx * 8 + 4) =
            make_float4(acc[r][4], acc[r][5], acc[r][6], acc[r][7]);
      }
    }
    __syncthreads();
    if (tz == 0) {
#pragma unroll
      for (int r = 0; r < 8; ++r) {
        const int sl = ty * 8 + r;
        const float4 v0 = *reinterpret_cast<const float4*>(xs + sl * DD + tx * 8);
        const float4 v1 = *reinterpret_cast<const float4*>(xs + sl * DD + tx * 8 + 4);
        acc[r][0] += v0.x; acc[r][1] += v0.y; acc[r][2] += v0.z; acc[r][3] += v0.w;
        acc[r][4] += v1.x; acc[r][5] += v1.y; acc[r][6] += v1.z; acc[r][7] += v1.w;
      }
    }
  }
  if (tz == 0) {
#pragma unroll
    for (int r = 0; r < 8; ++r) {
      const int sl = ty * 8 + r;
      float den = 0.0f;
#pragma unroll
      for (int q = 0; q < 8; ++q) den += denp[q * 32 + sl];
      const float inv = 1.0f / den;
      float* orow = out + ((size_t)b * SS + s0 + sl) * DD + tx * 8;
      *reinterpret_cast<float4*>(orow) =
          make_float4(acc[r][0] * inv, acc[r][1] * inv, acc[r][2] * inv, acc[r][3] * inv);
      *reinterpret_cast<float4*>(orow + 4) =
          make_float4(acc[r][4] * inv, acc[r][5] * inv, acc[r][6] * inv, acc[r][7] * inv);
    }
  }
}

extern "C" void kernel_launch(void* const* d_in, const int* in_sizes, int n_in,
                              void* d_out, int out_size, void* d_ws, size_t ws_size,
                              hipStream_t stream) {
  const float* X = (const float*)d_in[0];
  const float* rotp = (const float*)d_in[1];
  const float* entp = (const float*)d_in[2];
  float* out = (float*)d_out;
  uint8_t* ws = (uint8_t*)d_ws;

  if (ws_size >= WS_NEED) {
    prep<<<512, 256, 0, stream>>>(X, rotp, entp, ws, 1);
    attn_mfma<<<512, 512, 0, stream>>>((const uint8_t*)ws, out);
  } else {
    float* a2 = (float*)(ws + WS_A2);
    float* kv = (float*)(ws + WS_KV);
    float* kmxp = (float*)(ws + WS_KMX);
    float* kmnp = (float*)(ws + WS_KMN);
    prep<<<512, 256, 0, stream>>>(X, rotp, entp, ws, 0);
    kminmax<<<NB, 256, 0, stream>>>(kv, kmxp, kmnp);
    attn_main<<<dim3(SS / 32, NB), 256, 0, stream>>>(X, a2, kv, kmxp, kmnp, out);
  }
}